// Round 15
// baseline (990.609 us; speedup 1.0000x reference)
//
#include <hip/hip_runtime.h>
#include <hip/hip_bf16.h>
#include <math.h>

// Problem constants
#define BB    4
#define TT    1024
#define EE    256
#define HIDD  256
#define LLUT  8
#define HGT   384
#define WID   384
#define HWPX  147456      // 384*384
#define GSZ   33
#define G3    35937       // 33^3
#define NCOL  862488      // L*3*G3
#define NOUT3 107811      // 3*G3

typedef __attribute__((ext_vector_type(8))) short bf16x8;   // 8 bf16 = 4 VGPRs
typedef __attribute__((ext_vector_type(4))) float f32x4;

// fast gelu (tanh form): max abs dev from exact erf-gelu ~1e-3, threshold 2e-2
__device__ __forceinline__ float gelu_f(float x) {
    float s = 1.5957691216057308f * x * (1.0f + 0.044715f * x * x);
    float e = __expf(s);
    return x - x / (e + 1.0f);   // x*sigmoid(s); safe at +-inf
}

__device__ __forceinline__ ushort f2bf(float x) {
    uint u = __float_as_uint(x);
    return (ushort)((u + 0x7FFFu + ((u >> 16) & 1u)) >> 16);   // RNE
}
__device__ __forceinline__ uint pack2bf(float a, float b) {
    return (uint)f2bf(a) | ((uint)f2bf(b) << 16);
}
__device__ __forceinline__ float bf2f_lo(uint u) { return __uint_as_float(u << 16); }
__device__ __forceinline__ float bf2f_hi(uint u) { return __uint_as_float(u & 0xFFFF0000u); }

// ---------------------------------------------------------------------------
// lut worker: one (c,v) output of the fused LUT-GEMM+combine. hbuf holds
// h3[1024] then lwv[32] (loaded to LDS by caller).
// ---------------------------------------------------------------------------
__device__ __forceinline__ void lut_one(
    int idx, const float* __restrict__ hbuf,
    const float* __restrict__ w2, const float* __restrict__ b2,
    float* __restrict__ clut)
{
    if (idx >= NOUT3) return;
    const int c = idx / G3, v = idx - c * G3;
    const float* lws = hbuf + BB * HIDD;

    float acc[BB][LLUT];
#pragma unroll
    for (int b = 0; b < BB; ++b)
#pragma unroll
        for (int l = 0; l < LLUT; ++l) acc[b][l] = 0.f;

    const float* wbase = w2 + (long)c * G3 + v;   // + l*3*G3 + k*NCOL
#pragma unroll 4
    for (int k = 0; k < HIDD; ++k) {
        const float* row = wbase + (long)k * NCOL;
        float wl[LLUT];
#pragma unroll
        for (int l = 0; l < LLUT; ++l) wl[l] = row[l * 3 * G3];
#pragma unroll
        for (int b = 0; b < BB; ++b) {
            const float hb = hbuf[b * HIDD + k];
#pragma unroll
            for (int l = 0; l < LLUT; ++l) acc[b][l] += wl[l] * hb;
        }
    }

    float bb[LLUT];
#pragma unroll
    for (int l = 0; l < LLUT; ++l) bb[l] = b2[(long)(l * 3 + c) * G3 + v];

#pragma unroll
    for (int b = 0; b < BB; ++b) {
        float s = 0.f;
#pragma unroll
        for (int l = 0; l < LLUT; ++l) s += lws[b * LLUT + l] * (acc[b][l] + bb[l]);
        clut[(long)(b * 3 + c) * G3 + v] = s;
    }
}

// ---------------------------------------------------------------------------
// K-1: pack conv32 A-fragments for all 4 layers, lane-linear bf16.
// ---------------------------------------------------------------------------
__global__ __launch_bounds__(256) void pack_wconv_kernel(
    const float* __restrict__ w0, const float* __restrict__ w1,
    const float* __restrict__ w2, const float* __restrict__ w3,
    ushort* __restrict__ wpk)
{
    const int layer = blockIdx.x;
    const float* w = (layer == 0) ? w0 : (layer == 1) ? w1 : (layer == 2) ? w2 : w3;
    ushort* dst = wpk + layer * 9216;
    for (int i = threadIdx.x; i < 9216; i += 256) {
        const int j    = i & 7;
        const int lane = (i >> 3) & 63;
        const int half = (i >> 9) & 1;
        const int tap  = i >> 10;
        const int co = half * 16 + (lane & 15);
        const int ci = (lane >> 4) * 8 + j;
        dst[i] = f2bf(w[co * 288 + ci * 9 + tap]);
    }
}

// ---------------------------------------------------------------------------
// K0: embedding-mean partial sums. grid (64, B).
// ---------------------------------------------------------------------------
__global__ __launch_bounds__(256) void emb_partial_kernel(
    const int* __restrict__ tokens, const float* __restrict__ emb,
    float* __restrict__ partial)
{
    const int s = blockIdx.x, b = blockIdx.y, tid = threadIdx.x;
    const int* tok = tokens + b * TT + s * 16;
    float acc = 0.f;
#pragma unroll
    for (int t = 0; t < 16; ++t) acc += emb[tok[t] * EE + tid];
    partial[(b * 64 + s) * EE + tid] = acc;
}

// ---------------------------------------------------------------------------
// K1: fused token head, latency-parallel.
// ---------------------------------------------------------------------------
__global__ __launch_bounds__(1024) void mlp_head_kernel(
    const float* __restrict__ partial,
    const float* __restrict__ aw1, const float* __restrict__ ab1,
    const float* __restrict__ aw2, const float* __restrict__ ab2,
    const float* __restrict__ lw1, const float* __restrict__ lb1,
    const float* __restrict__ gw1, const float* __restrict__ gb1,
    const float* __restrict__ gw2, const float* __restrict__ gb2,
    float* __restrict__ h3_out, float* __restrict__ lw_out)
{
    const int b = blockIdx.x;
    const int tid = threadIdx.x;
    const int o = tid & 255;
    const int q = tid >> 8;
    __shared__ float tf[256], h1[256], tf2s[256], h4[64], lg[8];
    __shared__ float red[4][256];

    {
        float acc = 0.f;
#pragma unroll
        for (int s = 0; s < 16; ++s)
            acc += partial[(b * 64 + q * 16 + s) * EE + o];
        red[q][o] = acc;
    }
    __syncthreads();
    if (tid < 256)
        tf[tid] = (red[0][tid] + red[1][tid] + red[2][tid] + red[3][tid]) * (1.0f / TT);
    __syncthreads();

    {
        float s = 0.f;
#pragma unroll 8
        for (int j = 0; j < 64; ++j) {
            const int k = (q << 6) + j;
            s += tf[k] * aw1[k * HIDD + o];
        }
        red[q][o] = s;
    }
    __syncthreads();
    if (tid < 256)
        h1[tid] = gelu_f(red[0][tid] + red[1][tid] + red[2][tid] + red[3][tid] + ab1[tid]);
    __syncthreads();

    {
        float s = 0.f;
#pragma unroll 8
        for (int j = 0; j < 64; ++j) {
            const int k = (q << 6) + j;
            s += h1[k] * aw2[k * HIDD + o];
        }
        red[q][o] = s;
    }
    __syncthreads();
    if (tid < 256)
        tf2s[tid] = red[0][tid] + red[1][tid] + red[2][tid] + red[3][tid] + ab2[tid];
    __syncthreads();

    {
        float s = 0.f;
#pragma unroll 8
        for (int j = 0; j < 64; ++j) {
            const int k = (q << 6) + j;
            s += tf2s[k] * lw1[k * HIDD + o];
        }
        red[q][o] = s;
    }
    __syncthreads();
    if (tid < 256)
        h3_out[b * HIDD + tid] =
            gelu_f(red[0][tid] + red[1][tid] + red[2][tid] + red[3][tid] + lb1[tid]);
    __syncthreads();

    {
        const int o64 = tid & 63, q16 = tid >> 6;
        float s = 0.f;
#pragma unroll
        for (int j = 0; j < 16; ++j) {
            const int k = q16 * 16 + j;
            s += tf2s[k] * gw1[k * 64 + o64];
        }
        ((float*)red)[q16 * 64 + o64] = s;
    }
    __syncthreads();
    if (tid < 64) {
        float s = gb1[tid];
#pragma unroll
        for (int r = 0; r < 16; ++r) s += ((float*)red)[r * 64 + tid];
        h4[tid] = gelu_f(s);
    }
    __syncthreads();

    if (tid < 8) {
        float s = gb2[tid];
#pragma unroll 8
        for (int k = 0; k < 64; ++k) s += h4[k] * gw2[k * LLUT + tid];
        lg[tid] = s;
    }
    __syncthreads();
    if (tid == 0) {
        float m = lg[0];
        for (int i = 1; i < LLUT; ++i) m = fmaxf(m, lg[i]);
        float ssum = 0.f, ex[LLUT];
        for (int i = 0; i < LLUT; ++i) { ex[i] = expf(lg[i] - m); ssum += ex[i]; }
        for (int i = 0; i < LLUT; ++i) lw_out[b * LLUT + i] = ex[i] / ssum;
    }
}

// ---------------------------------------------------------------------------
// K5+lut: 3->32 conv (2 px/thread) with appended lut blocks [0, 27648).
// grid.x = 1152 + 108, 256 threads.
// ---------------------------------------------------------------------------
#define IN3_NB   1152   // 288 x 4
#define LUT1_NB  108    // 108*256 = 27648 outputs
#define LUT1_CNT 27648

__global__ __launch_bounds__(256) void conv_in3_lut_kernel(
    const float* __restrict__ img, const float* __restrict__ wgt,
    const float* __restrict__ bias, ushort* __restrict__ out,
    const float* __restrict__ h3, const float* __restrict__ lwv,
    const float* __restrict__ w2, const float* __restrict__ b2,
    float* __restrict__ clut)
{
    __shared__ float hbuf[BB * HIDD + BB * LLUT];
    const int tid = threadIdx.x;
    const int bid = blockIdx.x;

    if (bid >= IN3_NB) {
        // lut chunk A
        for (int i = tid; i < BB * HIDD; i += 256) hbuf[i] = h3[i];
        if (tid < BB * LLUT) hbuf[BB * HIDD + tid] = lwv[tid];
        __syncthreads();
        lut_one((bid - IN3_NB) * 256 + tid, hbuf, w2, b2, clut);
        return;
    }

    const int b = bid / 288, xb = bid - b * 288;
    const int p0 = (xb * 256 + tid) * 2;
    const int hh = p0 / WID, ww = p0 - hh * WID;

    float acc[32][2];
#pragma unroll
    for (int o = 0; o < 32; ++o) { float bv = bias[o]; acc[o][0] = bv; acc[o][1] = bv; }

    const bool wlo = (ww > 0), whi = (ww + 2 < WID);
#pragma unroll
    for (int ci = 0; ci < 3; ++ci) {
        const float* ip = img + (long)(b * 3 + ci) * HWPX;
        float x[3][4];
#pragma unroll
        for (int dh = 0; dh < 3; ++dh) {
            const int hs = hh + dh - 1;
            const bool hok = (hs >= 0) && (hs < HGT);
            const float* rp_ = ip + hs * WID + ww;
            x[dh][0] = (hok && wlo) ? rp_[-1] : 0.f;
            x[dh][1] = hok ? rp_[0] : 0.f;
            x[dh][2] = hok ? rp_[1] : 0.f;
            x[dh][3] = (hok && whi) ? rp_[2] : 0.f;
        }
#pragma unroll
        for (int o = 0; o < 32; ++o) {
            const float* wv = wgt + o * 27 + ci * 9;   // uniform -> s_load
#pragma unroll
            for (int dh = 0; dh < 3; ++dh)
#pragma unroll
                for (int dw = 0; dw < 3; ++dw) {
                    const float w = wv[dh * 3 + dw];
                    acc[o][0] += x[dh][dw]     * w;
                    acc[o][1] += x[dh][dw + 1] * w;
                }
        }
    }

    ushort* op = out + ((long)b * HWPX + p0) * 32;
#pragma unroll
    for (int px = 0; px < 2; ++px) {
        uint u[16];
#pragma unroll
        for (int o2 = 0; o2 < 16; ++o2)
            u[o2] = pack2bf(gelu_f(acc[2 * o2][px]), gelu_f(acc[2 * o2 + 1][px]));
        uint4* dst = (uint4*)(op + px * 32);
#pragma unroll
        for (int q = 0; q < 4; ++q)
            dst[q] = make_uint4(u[4 * q], u[4 * q + 1], u[4 * q + 2], u[4 * q + 3]);
    }
}

// ---------------------------------------------------------------------------
// K6+lut: MFMA 32->32 conv (r14 structure: pre-packed A, halo-only LDS,
// XCD swizzle) + appended 512-thread lut blocks (reuse halo LDS for hbuf).
// lut_off/lut blocks only on the two rp dispatches (fu dispatches launch
// grid=NBLK so the lut branch never runs).
// ---------------------------------------------------------------------------
#define TH2 8
#define TW2 64
#define NTX (WID / TW2)          // 6
#define NTY (HGT / TH2)          // 48
#define NBLK (NTX * NTY * BB)    // 1152
#define CHUNK (NBLK / 8)         // 144
#define HALO_H2 10
#define HALO_W2 66
#define CSTR 40   // padded ushort stride per pixel (80 B)

template <bool HAS_RES>
__global__ __launch_bounds__(512, 6) void conv32_mfma(
    const ushort* __restrict__ in, const ushort* __restrict__ res,
    const ushort* __restrict__ wpk, const float* __restrict__ bias,
    const float* __restrict__ bn_g, const float* __restrict__ bn_bt,
    ushort* __restrict__ out,
    const float* __restrict__ h3, const float* __restrict__ lwv,
    const float* __restrict__ w2, const float* __restrict__ b2,
    float* __restrict__ clut, int lut_off)
{
    __shared__ ushort halo[HALO_H2 * HALO_W2 * CSTR];   // 52800 B
    __shared__ float s_scale[32], s_shift[32];

    const int tid = threadIdx.x;
    const int bid = blockIdx.x;

    if (bid >= NBLK) {
        // lut chunk (512 outputs per block); reuse halo LDS for h/lws
        float* hbuf = (float*)halo;
        for (int i = tid; i < BB * HIDD; i += 512) hbuf[i] = h3[i];
        if (tid < BB * LLUT) hbuf[BB * HIDD + tid] = lwv[tid];
        __syncthreads();
        lut_one((bid - NBLK) * 512 + tid + lut_off, hbuf, w2, b2, clut);
        return;
    }

    // XCD-chunked bijective swizzle
    const int t   = (bid & 7) * CHUNK + (bid >> 3);
    const int tx  = t % NTX;
    const int rem = t / NTX;
    const int ty  = rem % NTY;
    const int b   = rem / NTY;
    const int h0 = ty * TH2;
    const int w0 = tx * TW2;

    if (tid < 32) {
        float sg = bn_g[tid] * 0.9999950000375f;   // g*(1+1e-5)^-0.5
        s_scale[tid] = sg;
        s_shift[tid] = bias[tid] * sg + bn_bt[tid];
    }

    // stage halo (zero-filled OOB); 16B chunks, coalesced NHWC reads
    const ushort* inb = in + (long)b * HWPX * 32;
    for (int i = tid; i < HALO_H2 * HALO_W2 * 4; i += 512) {
        const int row = i / (HALO_W2 * 4);
        const int rem2 = i - row * (HALO_W2 * 4);
        const int px = rem2 >> 2, q = rem2 & 3;
        const int gh = h0 + row - 1, gw = w0 + px - 1;
        uint4 v = make_uint4(0u, 0u, 0u, 0u);
        if (gh >= 0 && gh < HGT && gw >= 0 && gw < WID)
            v = *(const uint4*)(inb + ((long)gh * WID + gw) * 32 + q * 8);
        *(uint4*)(&halo[(row * HALO_W2 + px) * CSTR + q * 8]) = v;
    }
    __syncthreads();

    const int lane = tid & 63, wid = tid >> 6;
    const int l15 = lane & 15, kg = lane >> 4;
    const int r = wid;                      // one output row per wave
    const ushort* wlane = wpk + lane * 8;   // lane-linear A base

    f32x4 acc[4][2];
#pragma unroll
    for (int f = 0; f < 4; ++f)
#pragma unroll
        for (int cf = 0; cf < 2; ++cf)
            acc[f][cf] = (f32x4){0.f, 0.f, 0.f, 0.f};

#pragma unroll
    for (int tap = 0; tap < 9; ++tap) {
        const int dh = tap / 3, dw = tap - dh * 3;
        const bf16x8 a0 = *(const bf16x8*)(wlane + (tap * 2 + 0) * 512);
        const bf16x8 a1 = *(const bf16x8*)(wlane + (tap * 2 + 1) * 512);
#pragma unroll
        for (int f = 0; f < 4; ++f) {
            const int c0 = f * 16;
            const bf16x8 bfv = *(const bf16x8*)(
                &halo[((r + dh) * HALO_W2 + (c0 + dw + l15)) * CSTR + kg * 8]);
            acc[f][0] = __builtin_amdgcn_mfma_f32_16x16x32_bf16(a0, bfv, acc[f][0], 0, 0, 0);
            acc[f][1] = __builtin_amdgcn_mfma_f32_16x16x32_bf16(a1, bfv, acc[f][1], 0, 0, 0);
        }
    }

    // epilogue: scale/shift (+res) + gelu -> bf16 NHWC
#pragma unroll
    for (int f = 0; f < 4; ++f) {
        const int c0 = f * 16;
        const long gpx = (long)b * HWPX + (long)(h0 + r) * WID + (w0 + c0 + l15);
#pragma unroll
        for (int cf = 0; cf < 2; ++cf) {
            const int co0 = cf * 16 + kg * 4;
            const float4 sc = *(const float4*)(&s_scale[co0]);
            const float4 sh = *(const float4*)(&s_shift[co0]);
            float v0 = acc[f][cf][0] * sc.x + sh.x;
            float v1 = acc[f][cf][1] * sc.y + sh.y;
            float v2 = acc[f][cf][2] * sc.z + sh.z;
            float v3 = acc[f][cf][3] * sc.w + sh.w;
            if (HAS_RES) {
                const uint2 rv = *(const uint2*)(res + gpx * 32 + co0);
                v0 += bf2f_lo(rv.x); v1 += bf2f_hi(rv.x);
                v2 += bf2f_lo(rv.y); v3 += bf2f_hi(rv.y);
            }
            uint2 o;
            o.x = pack2bf(gelu_f(v0), gelu_f(v1));
            o.y = pack2bf(gelu_f(v2), gelu_f(v3));
            *(uint2*)(out + gpx * 32 + co0) = o;
        }
    }
}

// ---------------------------------------------------------------------------
// K4+K7 merged: trilinear LUT apply + 32->3 proc conv -> comb [px][8] bf16.
// ---------------------------------------------------------------------------
__global__ __launch_bounds__(256) void applylut_out3_kernel(
    const float* __restrict__ clut, const float* __restrict__ recon,
    const ushort* __restrict__ act2, const float* __restrict__ wgt,
    const float* __restrict__ bias, ushort* __restrict__ comb)
{
    const int p = blockIdx.x * 256 + threadIdx.x;
    const int b = blockIdx.y;

    // --- LUT part ---
    const float* rc = recon + (long)b * 3 * HWPX;
    float cr = fminf(fmaxf(rc[p] * 32.f, 0.f), 32.f);
    float cg = fminf(fmaxf(rc[HWPX + p] * 32.f, 0.f), 32.f);
    float cb = fminf(fmaxf(rc[2 * HWPX + p] * 32.f, 0.f), 32.f);
    float fr = fminf(floorf(cr), 31.f);
    float fg = fminf(floorf(cg), 31.f);
    float fb = fminf(floorf(cb), 31.f);
    float tr = cr - fr, tg = cg - fg, tb_ = cb - fb;
    int idx = (((int)fr * GSZ + (int)fg) * GSZ + (int)fb);
    float c[3];
#pragma unroll
    for (int ch = 0; ch < 3; ++ch) {
        const float* lut = clut + (long)(b * 3 + ch) * G3;
        float v000 = lut[idx],                  v001 = lut[idx + 1];
        float v010 = lut[idx + GSZ],            v011 = lut[idx + GSZ + 1];
        float v100 = lut[idx + GSZ * GSZ],      v101 = lut[idx + GSZ * GSZ + 1];
        float v110 = lut[idx + GSZ * GSZ + GSZ], v111 = lut[idx + GSZ * GSZ + GSZ + 1];
        float c00 = v000 + (v001 - v000) * tb_;
        float c01 = v010 + (v011 - v010) * tb_;
        float c10 = v100 + (v101 - v100) * tb_;
        float c11 = v110 + (v111 - v110) * tb_;
        float c0 = c00 + (c01 - c00) * tg;
        float c1 = c10 + (c11 - c10) * tg;
        c[ch] = c0 + (c1 - c0) * tr;
    }

    // --- proc 32->3 conv part ---
    const int hh = p / WID, ww = p - hh * WID;
    float acc[3] = {bias[0], bias[1], bias[2]};
#pragma unroll
    for (int tap = 0; tap < 9; ++tap) {
        const int dh = tap / 3, dw = tap - dh * 3;
        const int gh = hh + dh - 1, gw = ww + dw - 1;
        if (gh < 0 || gh >= HGT || gw < 0 || gw >= WID) continue;
        const uint4* xp = (const uint4*)(act2 + ((long)b * HWPX + gh * WID + gw) * 32);
        float xx[32];
#pragma unroll
        for (int q = 0; q < 4; ++q) {
            uint4 v = xp[q];
            xx[q * 8 + 0] = bf2f_lo(v.x); xx[q * 8 + 1] = bf2f_hi(v.x);
            xx[q * 8 + 2] = bf2f_lo(v.y); xx[q * 8 + 3] = bf2f_hi(v.y);
            xx[q * 8 + 4] = bf2f_lo(v.z); xx[q * 8 + 5] = bf2f_hi(v.z);
            xx[q * 8 + 6] = bf2f_lo(v.w); xx[q * 8 + 7] = bf2f_hi(v.w);
        }
#pragma unroll
        for (int o = 0; o < 3; ++o)
#pragma unroll
            for (int ci = 0; ci < 32; ++ci)
                acc[o] += xx[ci] * wgt[o * 288 + ci * 9 + tap];
    }

    // pack: x={l0,l1}, y={l2,-}, z={p0,p1}, w={p2,-}
    uint4 u;
    u.x = pack2bf(c[0], c[1]);
    u.y = pack2bf(c[2], 0.f);
    u.z = pack2bf(acc[0], acc[1]);
    u.w = pack2bf(acc[2], 0.f);
    *(uint4*)(comb + ((long)b * HWPX + p) * 8) = u;
}

// ---------------------------------------------------------------------------
// K8: 6->32 conv (comb BF16 [px][8] -> act NHWC bf16), gelu. 1 px/thread.
// ---------------------------------------------------------------------------
__global__ __launch_bounds__(256) void conv_in6_kernel(
    const ushort* __restrict__ comb, const float* __restrict__ wgt,
    const float* __restrict__ bias, ushort* __restrict__ out)
{
    const int p = blockIdx.x * 256 + threadIdx.x;
    const int b = blockIdx.y;
    const int hh = p / WID, ww = p - hh * WID;

    float acc[32];
#pragma unroll
    for (int o = 0; o < 32; ++o) acc[o] = bias[o];

#pragma unroll
    for (int tap = 0; tap < 9; ++tap) {
        const int dh = tap / 3, dw = tap - dh * 3;
        const int gh = hh + dh - 1, gw = ww + dw - 1;
        if (gh < 0 || gh >= HGT || gw < 0 || gw >= WID) continue;
        const uint4 v = *(const uint4*)(comb + ((long)b * HWPX + gh * WID + gw) * 8);
        const float xs[6] = {bf2f_lo(v.x), bf2f_hi(v.x), bf2f_lo(v.y),
                             bf2f_lo(v.z), bf2f_hi(v.z), bf2f_lo(v.w)};
#pragma unroll
        for (int o = 0; o < 32; ++o) {
            const float* wv = wgt + o * 54 + tap;   // uniform -> s_load
            acc[o] += xs[0] * wv[0]  + xs[1] * wv[9]  + xs[2] * wv[18]
                    + xs[3] * wv[27] + xs[4] * wv[36] + xs[5] * wv[45];
        }
    }

    ushort* op = out + ((long)b * HWPX + p) * 32;
    uint u[16];
#pragma unroll
    for (int o2 = 0; o2 < 16; ++o2)
        u[o2] = pack2bf(gelu_f(acc[2 * o2]), gelu_f(acc[2 * o2 + 1]));
    uint4* dst = (uint4*)op;
#pragma unroll
    for (int q = 0; q < 4; ++q)
        dst[q] = make_uint4(u[4 * q], u[4 * q + 1], u[4 * q + 2], u[4 * q + 3]);
}

// ---------------------------------------------------------------------------
// K9: final 32->3 conv (NHWC bf16) + img -> d_out fp32 NCHW. 1 px/thread.
// ---------------------------------------------------------------------------
__global__ __launch_bounds__(256) void conv_final_kernel(
    const ushort* __restrict__ in, const float* __restrict__ wgt,
    const float* __restrict__ bias, const float* __restrict__ img,
    float* __restrict__ outp)
{
    const int p = blockIdx.x * 256 + threadIdx.x;
    const int b = blockIdx.y;
    const int hh = p / WID, ww = p - hh * WID;
    float acc[3] = {bias[0], bias[1], bias[2]};

#pragma unroll
    for (int tap = 0; tap < 9; ++tap) {
        const int dh = tap / 3, dw = tap - dh * 3;
        const int gh = hh + dh - 1, gw = ww + dw - 1;
        if (gh < 0 || gh >= HGT || gw < 0 || gw >= WID) continue;
        const uint4* xp = (const uint4*)(in + ((long)b * HWPX + gh * WID + gw) * 32);
        float xx[32];
#pragma unroll
        for (int q = 0; q < 4; ++q) {
            uint4 v = xp[q];
            xx[q * 8 + 0] = bf2f_lo(v.x); xx[q * 8 + 1] = bf2f_hi(v.x);
            xx[q * 8 + 2] = bf2f_lo(v.y); xx[q * 8 + 3] = bf2f_hi(v.y);
            xx[q * 8 + 4] = bf2f_lo(v.z); xx[q * 8 + 5] = bf2f_hi(v.z);
            xx[q * 8 + 6] = bf2f_lo(v.w); xx[q * 8 + 7] = bf2f_hi(v.w);
        }
#pragma unroll
        for (int o = 0; o < 3; ++o)
#pragma unroll
            for (int ci = 0; ci < 32; ++ci)
                acc[o] += xx[ci] * wgt[o * 288 + ci * 9 + tap];
    }
#pragma unroll
    for (int o = 0; o < 3; ++o)
        outp[(long)(b * 3 + o) * HWPX + p] = acc[o] + img[(long)(b * 3 + o) * HWPX + p];
}

// ---------------------------------------------------------------------------
extern "C" void kernel_launch(void* const* d_in, const int* in_sizes, int n_in,
                              void* d_out, int out_size, void* d_ws, size_t ws_size,
                              hipStream_t stream)
{
    const int*   tokens  = (const int*)d_in[0];
    const float* img     = (const float*)d_in[1];
    const float* recon   = (const float*)d_in[2];
    const float* emb     = (const float*)d_in[3];
    const float* agg_w1  = (const float*)d_in[4];
    const float* agg_b1  = (const float*)d_in[5];
    const float* agg_w2  = (const float*)d_in[6];
    const float* agg_b2  = (const float*)d_in[7];
    const float* lut_w1  = (const float*)d_in[8];
    const float* lut_b1  = (const float*)d_in[9];
    const float* lut_w2  = (const float*)d_in[10];
    const float* lut_b2  = (const float*)d_in[11];
    const float* wg_w1   = (const float*)d_in[12];
    const float* wg_b1   = (const float*)d_in[13];
    const float* wg_w2   = (const float*)d_in[14];
    const float* wg_b2   = (const float*)d_in[15];
    const float* rp_cin_w = (const float*)d_in[16];
    const float* rp_cin_b = (const float*)d_in[17];
    const float* rp_rbA_w = (const float*)d_in[18];
    const float* rp_rbA_b = (const float*)d_in[19];
    const float* rp_rbA_g = (const float*)d_in[20];
    const float* rp_rbA_bt= (const float*)d_in[21];
    const float* rp_rbB_w = (const float*)d_in[22];
    const float* rp_rbB_b = (const float*)d_in[23];
    const float* rp_rbB_g = (const float*)d_in[24];
    const float* rp_rbB_bt= (const float*)d_in[25];
    const float* rp_cout_w= (const float*)d_in[26];
    const float* rp_cout_b= (const float*)d_in[27];
    const float* fu_cin_w = (const float*)d_in[28];
    const float* fu_cin_b = (const float*)d_in[29];
    const float* fu_rbA_w = (const float*)d_in[30];
    const float* fu_rbA_b = (const float*)d_in[31];
    const float* fu_rbA_g = (const float*)d_in[32];
    const float* fu_rbA_bt= (const float*)d_in[33];
    const float* fu_rbB_w = (const float*)d_in[34];
    const float* fu_rbB_b = (const float*)d_in[35];
    const float* fu_rbB_g = (const float*)d_in[36];
    const float* fu_rbB_bt= (const float*)d_in[37];
    const float* fu_cout_w= (const float*)d_in[38];
    const float* fu_cout_b= (const float*)d_in[39];

    float* ws = (float*)d_ws;
    float*  h3      = ws;                       // 1024
    float*  lwv     = ws + 1024;                // 32
    float*  partial = ws + 2048;                // 65536
    float*  clut    = ws + 69632;               // 431244
    ushort* wpack   = (ushort*)(ws + 524288);   // 4*9216 ushorts
    ushort* comb    = (ushort*)(ws + 589824);   // 4*HWPX*8 ushorts (bf16)
    ushort* act0    = (ushort*)(ws + 3145728);  // 18874368 ushorts
    ushort* act1    = (ushort*)(ws + 12582912);
    ushort* act2    = (ushort*)(ws + 22020096);
    float*  outp    = (float*)d_out;

    // lut chunk split: [0,27648) in conv_in3; [27648,68096) in rpA;
    // [68096,107811) in rpB
    const int LUT2_NB = 79;    // 79*512 = 40448
    const int LUT3_NB = 78;    // 78*512 = 39936 (guarded)
    const int OFF2 = 27648, OFF3 = 68096;

    // pack conv32 A-fragments once (layers: rpA, rpB, fuA, fuB)
    pack_wconv_kernel<<<dim3(4), dim3(256), 0, stream>>>(
        rp_rbA_w, rp_rbB_w, fu_rbA_w, fu_rbB_w, wpack);

    // token head
    emb_partial_kernel<<<dim3(64, BB), dim3(256), 0, stream>>>(tokens, emb, partial);
    mlp_head_kernel<<<dim3(BB), dim3(1024), 0, stream>>>(
        partial, agg_w1, agg_b1, agg_w2, agg_b2,
        lut_w1, lut_b1, wg_w1, wg_b1, wg_w2, wg_b2, h3, lwv);

    const dim3 g1(HWPX / 256, BB), blk(256);

    // proc branch with lut blocks riding along (overlap: lut is BW-bound,
    // convs are compute-bound -> co-scheduled waves fill both pipes)
    conv_in3_lut_kernel<<<dim3(IN3_NB + LUT1_NB), blk, 0, stream>>>(
        img, rp_cin_w, rp_cin_b, act0, h3, lwv, lut_w2, lut_b2, clut);
    conv32_mfma<false><<<dim3(NBLK + LUT2_NB), dim3(512), 0, stream>>>(
        act0, nullptr, wpack + 0 * 9216, rp_rbA_b, rp_rbA_g, rp_rbA_bt, act1,
        h3, lwv, lut_w2, lut_b2, clut, OFF2);
    conv32_mfma<true><<<dim3(NBLK + LUT3_NB), dim3(512), 0, stream>>>(
        act1, act0, wpack + 1 * 9216, rp_rbB_b, rp_rbB_g, rp_rbB_bt, act2,
        h3, lwv, lut_w2, lut_b2, clut, OFF3);

    // merged: LUT apply + proc 32->3 -> comb (bf16)
    applylut_out3_kernel<<<g1, blk, 0, stream>>>(
        clut, recon, act2, rp_cout_w, rp_cout_b, comb);

    // fuse branch: comb -> act0 -> act1 -> act2 -> d_out (+img)
    conv_in6_kernel<<<g1, blk, 0, stream>>>(comb, fu_cin_w, fu_cin_b, act0);
    conv32_mfma<false><<<dim3(NBLK), dim3(512), 0, stream>>>(
        act0, nullptr, wpack + 2 * 9216, fu_rbA_b, fu_rbA_g, fu_rbA_bt, act1,
        h3, lwv, lut_w2, lut_b2, clut, 0);
    conv32_mfma<true><<<dim3(NBLK), dim3(512), 0, stream>>>(
        act1, act0, wpack + 3 * 9216, fu_rbB_b, fu_rbB_g, fu_rbB_bt, act2,
        h3, lwv, lut_w2, lut_b2, clut, 0);
    conv_final_kernel<<<g1, blk, 0, stream>>>(act2, fu_cout_w, fu_cout_b, img, outp);
}

// Round 16
// 552.179 us; speedup vs baseline: 1.7940x; 1.7940x over previous
//
#include <hip/hip_runtime.h>
#include <hip/hip_bf16.h>
#include <math.h>

// Problem constants
#define BB    4
#define TT    1024
#define EE    256
#define HIDD  256
#define LLUT  8
#define HGT   384
#define WID   384
#define HWPX  147456      // 384*384
#define GSZ   33
#define G3    35937       // 33^3
#define NCOL  862488      // L*3*G3

typedef __attribute__((ext_vector_type(8))) short bf16x8;   // 8 bf16 = 4 VGPRs
typedef __attribute__((ext_vector_type(4))) float f32x4;

// fast gelu (tanh form): max abs dev from exact erf-gelu ~1e-3, threshold 2e-2
__device__ __forceinline__ float gelu_f(float x) {
    float s = 1.5957691216057308f * x * (1.0f + 0.044715f * x * x);
    float e = __expf(s);
    return x - x / (e + 1.0f);   // x*sigmoid(s); safe at +-inf
}

__device__ __forceinline__ ushort f2bf(float x) {
    uint u = __float_as_uint(x);
    return (ushort)((u + 0x7FFFu + ((u >> 16) & 1u)) >> 16);   // RNE
}
__device__ __forceinline__ uint pack2bf(float a, float b) {
    return (uint)f2bf(a) | ((uint)f2bf(b) << 16);
}
__device__ __forceinline__ float bf2f_lo(uint u) { return __uint_as_float(u << 16); }
__device__ __forceinline__ float bf2f_hi(uint u) { return __uint_as_float(u & 0xFFFF0000u); }

// ---------------------------------------------------------------------------
// K-1: pack conv32 A-fragments for all 4 layers, lane-linear bf16.
// wpk[layer][(tap*2+half)*512 + lane*8 + j] = bf16(W[half*16+(lane&15)]
//                                                  [(lane>>4)*8+j][tap])
// 18.4 KB per layer -> L1-resident on each CU during conv32.
// ---------------------------------------------------------------------------
__global__ __launch_bounds__(256) void pack_wconv_kernel(
    const float* __restrict__ w0, const float* __restrict__ w1,
    const float* __restrict__ w2, const float* __restrict__ w3,
    ushort* __restrict__ wpk)
{
    const int layer = blockIdx.x;
    const float* w = (layer == 0) ? w0 : (layer == 1) ? w1 : (layer == 2) ? w2 : w3;
    ushort* dst = wpk + layer * 9216;
    for (int i = threadIdx.x; i < 9216; i += 256) {
        const int j    = i & 7;
        const int lane = (i >> 3) & 63;
        const int half = (i >> 9) & 1;
        const int tap  = i >> 10;
        const int co = half * 16 + (lane & 15);
        const int ci = (lane >> 4) * 8 + j;
        dst[i] = f2bf(w[co * 288 + ci * 9 + tap]);
    }
}

// ---------------------------------------------------------------------------
// K0: embedding-mean partial sums. grid (64, B).
// ---------------------------------------------------------------------------
__global__ __launch_bounds__(256) void emb_partial_kernel(
    const int* __restrict__ tokens, const float* __restrict__ emb,
    float* __restrict__ partial)
{
    const int s = blockIdx.x, b = blockIdx.y, tid = threadIdx.x;
    const int* tok = tokens + b * TT + s * 16;
    float acc = 0.f;
#pragma unroll
    for (int t = 0; t < 16; ++t) acc += emb[tok[t] * EE + tid];
    partial[(b * 64 + s) * EE + tid] = acc;
}

// ---------------------------------------------------------------------------
// K1: fused token head, latency-parallel (r7 version, measured-good).
// ---------------------------------------------------------------------------
__global__ __launch_bounds__(1024) void mlp_head_kernel(
    const float* __restrict__ partial,
    const float* __restrict__ aw1, const float* __restrict__ ab1,
    const float* __restrict__ aw2, const float* __restrict__ ab2,
    const float* __restrict__ lw1, const float* __restrict__ lb1,
    const float* __restrict__ gw1, const float* __restrict__ gb1,
    const float* __restrict__ gw2, const float* __restrict__ gb2,
    float* __restrict__ h3_out, float* __restrict__ lw_out)
{
    const int b = blockIdx.x;
    const int tid = threadIdx.x;
    const int o = tid & 255;
    const int q = tid >> 8;
    __shared__ float tf[256], h1[256], tf2s[256], h4[64], lg[8];
    __shared__ float red[4][256];

    {
        float acc = 0.f;
#pragma unroll
        for (int s = 0; s < 16; ++s)
            acc += partial[(b * 64 + q * 16 + s) * EE + o];
        red[q][o] = acc;
    }
    __syncthreads();
    if (tid < 256)
        tf[tid] = (red[0][tid] + red[1][tid] + red[2][tid] + red[3][tid]) * (1.0f / TT);
    __syncthreads();

    {
        float s = 0.f;
#pragma unroll 8
        for (int j = 0; j < 64; ++j) {
            const int k = (q << 6) + j;
            s += tf[k] * aw1[k * HIDD + o];
        }
        red[q][o] = s;
    }
    __syncthreads();
    if (tid < 256)
        h1[tid] = gelu_f(red[0][tid] + red[1][tid] + red[2][tid] + red[3][tid] + ab1[tid]);
    __syncthreads();

    {
        float s = 0.f;
#pragma unroll 8
        for (int j = 0; j < 64; ++j) {
            const int k = (q << 6) + j;
            s += h1[k] * aw2[k * HIDD + o];
        }
        red[q][o] = s;
    }
    __syncthreads();
    if (tid < 256)
        tf2s[tid] = red[0][tid] + red[1][tid] + red[2][tid] + red[3][tid] + ab2[tid];
    __syncthreads();

    {
        float s = 0.f;
#pragma unroll 8
        for (int j = 0; j < 64; ++j) {
            const int k = (q << 6) + j;
            s += tf2s[k] * lw1[k * HIDD + o];
        }
        red[q][o] = s;
    }
    __syncthreads();
    if (tid < 256)
        h3_out[b * HIDD + tid] =
            gelu_f(red[0][tid] + red[1][tid] + red[2][tid] + red[3][tid] + lb1[tid]);
    __syncthreads();

    {
        const int o64 = tid & 63, q16 = tid >> 6;
        float s = 0.f;
#pragma unroll
        for (int j = 0; j < 16; ++j) {
            const int k = q16 * 16 + j;
            s += tf2s[k] * gw1[k * 64 + o64];
        }
        ((float*)red)[q16 * 64 + o64] = s;
    }
    __syncthreads();
    if (tid < 64) {
        float s = gb1[tid];
#pragma unroll
        for (int r = 0; r < 16; ++r) s += ((float*)red)[r * 64 + tid];
        h4[tid] = gelu_f(s);
    }
    __syncthreads();

    if (tid < 8) {
        float s = gb2[tid];
#pragma unroll 8
        for (int k = 0; k < 64; ++k) s += h4[k] * gw2[k * LLUT + tid];
        lg[tid] = s;
    }
    __syncthreads();
    if (tid == 0) {
        float m = lg[0];
        for (int i = 1; i < LLUT; ++i) m = fmaxf(m, lg[i]);
        float ssum = 0.f, ex[LLUT];
        for (int i = 0; i < LLUT; ++i) { ex[i] = expf(lg[i] - m); ssum += ex[i]; }
        for (int i = 0; i < LLUT; ++i) lw_out[b * LLUT + i] = ex[i] / ssum;
    }
}

// ---------------------------------------------------------------------------
// K2: fused LUT-GEMM + softmax-combine -> clut (883 MB w2 stream, ~140 us).
// ---------------------------------------------------------------------------
__global__ __launch_bounds__(256) void lut_fused_kernel(
    const float* __restrict__ h3, const float* __restrict__ lwv,
    const float* __restrict__ w2, const float* __restrict__ b2,
    float* __restrict__ clut)
{
    __shared__ float h[BB * HIDD];
    __shared__ float lws[BB * LLUT];
    const int tid = threadIdx.x;
    for (int i = tid; i < BB * HIDD; i += 256) h[i] = h3[i];
    if (tid < BB * LLUT) lws[tid] = lwv[tid];
    __syncthreads();

    const int idx = blockIdx.x * 256 + tid;
    if (idx >= 3 * G3) return;
    const int c = idx / G3, v = idx - c * G3;

    float acc[BB][LLUT];
#pragma unroll
    for (int b = 0; b < BB; ++b)
#pragma unroll
        for (int l = 0; l < LLUT; ++l) acc[b][l] = 0.f;

    const float* wbase = w2 + (long)c * G3 + v;   // + l*3*G3 + k*NCOL
#pragma unroll 4
    for (int k = 0; k < HIDD; ++k) {
        const float* row = wbase + (long)k * NCOL;
        float wl[LLUT];
#pragma unroll
        for (int l = 0; l < LLUT; ++l) wl[l] = row[l * 3 * G3];
#pragma unroll
        for (int b = 0; b < BB; ++b) {
            const float hb = h[b * HIDD + k];
#pragma unroll
            for (int l = 0; l < LLUT; ++l) acc[b][l] += wl[l] * hb;
        }
    }

    float bb[LLUT];
#pragma unroll
    for (int l = 0; l < LLUT; ++l) bb[l] = b2[(long)(l * 3 + c) * G3 + v];

#pragma unroll
    for (int b = 0; b < BB; ++b) {
        float s = 0.f;
#pragma unroll
        for (int l = 0; l < LLUT; ++l) s += lws[b * LLUT + l] * (acc[b][l] + bb[l]);
        clut[(long)(b * 3 + c) * G3 + v] = s;
    }
}

// ---------------------------------------------------------------------------
// K4+K7 merged: trilinear LUT apply (comb bf16 slots 0..2) + 32->3 proc conv
// from act2 (slots 4..6) -> comb [px][8] BF16 (16 B/px, halves traffic).
// ---------------------------------------------------------------------------
__global__ __launch_bounds__(256) void applylut_out3_kernel(
    const float* __restrict__ clut, const float* __restrict__ recon,
    const ushort* __restrict__ act2, const float* __restrict__ wgt,
    const float* __restrict__ bias, ushort* __restrict__ comb)
{
    const int p = blockIdx.x * 256 + threadIdx.x;
    const int b = blockIdx.y;

    // --- LUT part ---
    const float* rc = recon + (long)b * 3 * HWPX;
    float cr = fminf(fmaxf(rc[p] * 32.f, 0.f), 32.f);
    float cg = fminf(fmaxf(rc[HWPX + p] * 32.f, 0.f), 32.f);
    float cb = fminf(fmaxf(rc[2 * HWPX + p] * 32.f, 0.f), 32.f);
    float fr = fminf(floorf(cr), 31.f);
    float fg = fminf(floorf(cg), 31.f);
    float fb = fminf(floorf(cb), 31.f);
    float tr = cr - fr, tg = cg - fg, tb_ = cb - fb;
    int idx = (((int)fr * GSZ + (int)fg) * GSZ + (int)fb);
    float c[3];
#pragma unroll
    for (int ch = 0; ch < 3; ++ch) {
        const float* lut = clut + (long)(b * 3 + ch) * G3;
        float v000 = lut[idx],                  v001 = lut[idx + 1];
        float v010 = lut[idx + GSZ],            v011 = lut[idx + GSZ + 1];
        float v100 = lut[idx + GSZ * GSZ],      v101 = lut[idx + GSZ * GSZ + 1];
        float v110 = lut[idx + GSZ * GSZ + GSZ], v111 = lut[idx + GSZ * GSZ + GSZ + 1];
        float c00 = v000 + (v001 - v000) * tb_;
        float c01 = v010 + (v011 - v010) * tb_;
        float c10 = v100 + (v101 - v100) * tb_;
        float c11 = v110 + (v111 - v110) * tb_;
        float c0 = c00 + (c01 - c00) * tg;
        float c1 = c10 + (c11 - c10) * tg;
        c[ch] = c0 + (c1 - c0) * tr;
    }

    // --- proc 32->3 conv part ---
    const int hh = p / WID, ww = p - hh * WID;
    float acc[3] = {bias[0], bias[1], bias[2]};
#pragma unroll
    for (int tap = 0; tap < 9; ++tap) {
        const int dh = tap / 3, dw = tap - dh * 3;
        const int gh = hh + dh - 1, gw = ww + dw - 1;
        if (gh < 0 || gh >= HGT || gw < 0 || gw >= WID) continue;
        const uint4* xp = (const uint4*)(act2 + ((long)b * HWPX + gh * WID + gw) * 32);
        float xx[32];
#pragma unroll
        for (int q = 0; q < 4; ++q) {
            uint4 v = xp[q];
            xx[q * 8 + 0] = bf2f_lo(v.x); xx[q * 8 + 1] = bf2f_hi(v.x);
            xx[q * 8 + 2] = bf2f_lo(v.y); xx[q * 8 + 3] = bf2f_hi(v.y);
            xx[q * 8 + 4] = bf2f_lo(v.z); xx[q * 8 + 5] = bf2f_hi(v.z);
            xx[q * 8 + 6] = bf2f_lo(v.w); xx[q * 8 + 7] = bf2f_hi(v.w);
        }
#pragma unroll
        for (int o = 0; o < 3; ++o)
#pragma unroll
            for (int ci = 0; ci < 32; ++ci)
                acc[o] += xx[ci] * wgt[o * 288 + ci * 9 + tap];
    }

    // pack: x={l0,l1}, y={l2,-}, z={p0,p1}, w={p2,-}
    uint4 u;
    u.x = pack2bf(c[0], c[1]);
    u.y = pack2bf(c[2], 0.f);
    u.z = pack2bf(acc[0], acc[1]);
    u.w = pack2bf(acc[2], 0.f);
    *(uint4*)(comb + ((long)b * HWPX + p) * 8) = u;
}

// ---------------------------------------------------------------------------
// K5: 3->32 conv (img fp32 NCHW -> act NHWC bf16), gelu. 2 px/thread.
// ---------------------------------------------------------------------------
__global__ __launch_bounds__(256) void conv_in3_kernel(
    const float* __restrict__ img, const float* __restrict__ wgt,
    const float* __restrict__ bias, ushort* __restrict__ out)
{
    const int tid = threadIdx.x;
    const int p0 = (blockIdx.x * 256 + tid) * 2;
    const int b = blockIdx.y;
    const int hh = p0 / WID, ww = p0 - hh * WID;

    float acc[32][2];
#pragma unroll
    for (int o = 0; o < 32; ++o) { float bv = bias[o]; acc[o][0] = bv; acc[o][1] = bv; }

    const bool wlo = (ww > 0), whi = (ww + 2 < WID);
#pragma unroll
    for (int ci = 0; ci < 3; ++ci) {
        const float* ip = img + (long)(b * 3 + ci) * HWPX;
        float x[3][4];
#pragma unroll
        for (int dh = 0; dh < 3; ++dh) {
            const int hs = hh + dh - 1;
            const bool hok = (hs >= 0) && (hs < HGT);
            const float* rp_ = ip + hs * WID + ww;
            x[dh][0] = (hok && wlo) ? rp_[-1] : 0.f;
            x[dh][1] = hok ? rp_[0] : 0.f;
            x[dh][2] = hok ? rp_[1] : 0.f;
            x[dh][3] = (hok && whi) ? rp_[2] : 0.f;
        }
#pragma unroll
        for (int o = 0; o < 32; ++o) {
            const float* wv = wgt + o * 27 + ci * 9;   // uniform -> s_load
#pragma unroll
            for (int dh = 0; dh < 3; ++dh)
#pragma unroll
                for (int dw = 0; dw < 3; ++dw) {
                    const float w = wv[dh * 3 + dw];
                    acc[o][0] += x[dh][dw]     * w;
                    acc[o][1] += x[dh][dw + 1] * w;
                }
        }
    }

    ushort* op = out + ((long)b * HWPX + p0) * 32;
#pragma unroll
    for (int px = 0; px < 2; ++px) {
        uint u[16];
#pragma unroll
        for (int o2 = 0; o2 < 16; ++o2)
            u[o2] = pack2bf(gelu_f(acc[2 * o2][px]), gelu_f(acc[2 * o2 + 1][px]));
        uint4* dst = (uint4*)(op + px * 32);
#pragma unroll
        for (int q = 0; q < 4; ++q)
            dst[q] = make_uint4(u[4 * q], u[4 * q + 1], u[4 * q + 2], u[4 * q + 3]);
    }
}

// ---------------------------------------------------------------------------
// K6 v4: MFMA 32->32 conv. A-frags PRE-PACKED in global (lane-linear 1KB/wave
// loads, L1-resident 18.4 KB) -> no per-block pack, LDS = halo only (52.8 KB)
// -> 3 blocks/CU. XCD-chunked bijective swizzle.
// Tile 8 rows x 64 px, 8 waves. Halo 10x66, CSTR=40 (conflict-free b128).
// ---------------------------------------------------------------------------
#define TH2 8
#define TW2 64
#define NTX (WID / TW2)          // 6
#define NTY (HGT / TH2)          // 48
#define NBLK (NTX * NTY * BB)    // 1152
#define CHUNK (NBLK / 8)         // 144
#define HALO_H2 10
#define HALO_W2 66
#define CSTR 40   // padded ushort stride per pixel (80 B)

template <bool HAS_RES>
__global__ __launch_bounds__(512, 6) void conv32_mfma(
    const ushort* __restrict__ in, const ushort* __restrict__ res,
    const ushort* __restrict__ wpk, const float* __restrict__ bias,
    const float* __restrict__ bn_g, const float* __restrict__ bn_bt,
    ushort* __restrict__ out)
{
    __shared__ ushort halo[HALO_H2 * HALO_W2 * CSTR];   // 52800 B
    __shared__ float s_scale[32], s_shift[32];

    const int tid = threadIdx.x;
    // XCD-chunked bijective swizzle
    const int bid = blockIdx.x;
    const int t   = (bid & 7) * CHUNK + (bid >> 3);
    const int tx  = t % NTX;
    const int rem = t / NTX;
    const int ty  = rem % NTY;
    const int b   = rem / NTY;
    const int h0 = ty * TH2;
    const int w0 = tx * TW2;

    if (tid < 32) {
        float sg = bn_g[tid] * 0.9999950000375f;   // g*(1+1e-5)^-0.5
        s_scale[tid] = sg;
        s_shift[tid] = bias[tid] * sg + bn_bt[tid];
    }

    // stage halo (zero-filled OOB); 16B chunks, coalesced NHWC reads
    const ushort* inb = in + (long)b * HWPX * 32;
    for (int i = tid; i < HALO_H2 * HALO_W2 * 4; i += 512) {
        const int row = i / (HALO_W2 * 4);
        const int rem2 = i - row * (HALO_W2 * 4);
        const int px = rem2 >> 2, q = rem2 & 3;
        const int gh = h0 + row - 1, gw = w0 + px - 1;
        uint4 v = make_uint4(0u, 0u, 0u, 0u);
        if (gh >= 0 && gh < HGT && gw >= 0 && gw < WID)
            v = *(const uint4*)(inb + ((long)gh * WID + gw) * 32 + q * 8);
        *(uint4*)(&halo[(row * HALO_W2 + px) * CSTR + q * 8]) = v;
    }
    __syncthreads();

    const int lane = tid & 63, wid = tid >> 6;
    const int l15 = lane & 15, kg = lane >> 4;
    const int r = wid;                      // one output row per wave
    const ushort* wlane = wpk + lane * 8;   // lane-linear A base

    f32x4 acc[4][2];
#pragma unroll
    for (int f = 0; f < 4; ++f)
#pragma unroll
        for (int cf = 0; cf < 2; ++cf)
            acc[f][cf] = (f32x4){0.f, 0.f, 0.f, 0.f};

#pragma unroll
    for (int tap = 0; tap < 9; ++tap) {
        const int dh = tap / 3, dw = tap - dh * 3;
        const bf16x8 a0 = *(const bf16x8*)(wlane + (tap * 2 + 0) * 512);
        const bf16x8 a1 = *(const bf16x8*)(wlane + (tap * 2 + 1) * 512);
#pragma unroll
        for (int f = 0; f < 4; ++f) {
            const int c0 = f * 16;
            const bf16x8 bfv = *(const bf16x8*)(
                &halo[((r + dh) * HALO_W2 + (c0 + dw + l15)) * CSTR + kg * 8]);
            acc[f][0] = __builtin_amdgcn_mfma_f32_16x16x32_bf16(a0, bfv, acc[f][0], 0, 0, 0);
            acc[f][1] = __builtin_amdgcn_mfma_f32_16x16x32_bf16(a1, bfv, acc[f][1], 0, 0, 0);
        }
    }

    // epilogue: scale/shift (+res) + gelu -> bf16 NHWC
#pragma unroll
    for (int f = 0; f < 4; ++f) {
        const int c0 = f * 16;
        const long gpx = (long)b * HWPX + (long)(h0 + r) * WID + (w0 + c0 + l15);
#pragma unroll
        for (int cf = 0; cf < 2; ++cf) {
            const int co0 = cf * 16 + kg * 4;
            const float4 sc = *(const float4*)(&s_scale[co0]);
            const float4 sh = *(const float4*)(&s_shift[co0]);
            float v0 = acc[f][cf][0] * sc.x + sh.x;
            float v1 = acc[f][cf][1] * sc.y + sh.y;
            float v2 = acc[f][cf][2] * sc.z + sh.z;
            float v3 = acc[f][cf][3] * sc.w + sh.w;
            if (HAS_RES) {
                const uint2 rv = *(const uint2*)(res + gpx * 32 + co0);
                v0 += bf2f_lo(rv.x); v1 += bf2f_hi(rv.x);
                v2 += bf2f_lo(rv.y); v3 += bf2f_hi(rv.y);
            }
            uint2 o;
            o.x = pack2bf(gelu_f(v0), gelu_f(v1));
            o.y = pack2bf(gelu_f(v2), gelu_f(v3));
            *(uint2*)(out + gpx * 32 + co0) = o;
        }
    }
}

// ---------------------------------------------------------------------------
// K8: 6->32 conv (comb BF16 [px][8] -> act NHWC bf16), gelu. 1 px/thread.
// ---------------------------------------------------------------------------
__global__ __launch_bounds__(256) void conv_in6_kernel(
    const ushort* __restrict__ comb, const float* __restrict__ wgt,
    const float* __restrict__ bias, ushort* __restrict__ out)
{
    const int p = blockIdx.x * 256 + threadIdx.x;
    const int b = blockIdx.y;
    const int hh = p / WID, ww = p - hh * WID;

    float acc[32];
#pragma unroll
    for (int o = 0; o < 32; ++o) acc[o] = bias[o];

#pragma unroll
    for (int tap = 0; tap < 9; ++tap) {
        const int dh = tap / 3, dw = tap - dh * 3;
        const int gh = hh + dh - 1, gw = ww + dw - 1;
        if (gh < 0 || gh >= HGT || gw < 0 || gw >= WID) continue;
        const uint4 v = *(const uint4*)(comb + ((long)b * HWPX + gh * WID + gw) * 8);
        const float xs[6] = {bf2f_lo(v.x), bf2f_hi(v.x), bf2f_lo(v.y),
                             bf2f_lo(v.z), bf2f_hi(v.z), bf2f_lo(v.w)};
#pragma unroll
        for (int o = 0; o < 32; ++o) {
            const float* wv = wgt + o * 54 + tap;   // uniform -> s_load
            acc[o] += xs[0] * wv[0]  + xs[1] * wv[9]  + xs[2] * wv[18]
                    + xs[3] * wv[27] + xs[4] * wv[36] + xs[5] * wv[45];
        }
    }

    ushort* op = out + ((long)b * HWPX + p) * 32;
    uint u[16];
#pragma unroll
    for (int o2 = 0; o2 < 16; ++o2)
        u[o2] = pack2bf(gelu_f(acc[2 * o2]), gelu_f(acc[2 * o2 + 1]));
    uint4* dst = (uint4*)op;
#pragma unroll
    for (int q = 0; q < 4; ++q)
        dst[q] = make_uint4(u[4 * q], u[4 * q + 1], u[4 * q + 2], u[4 * q + 3]);
}

// ---------------------------------------------------------------------------
// K9: final 32->3 conv (NHWC bf16) + img -> d_out fp32 NCHW. 1 px/thread.
// ---------------------------------------------------------------------------
__global__ __launch_bounds__(256) void conv_final_kernel(
    const ushort* __restrict__ in, const float* __restrict__ wgt,
    const float* __restrict__ bias, const float* __restrict__ img,
    float* __restrict__ outp)
{
    const int p = blockIdx.x * 256 + threadIdx.x;
    const int b = blockIdx.y;
    const int hh = p / WID, ww = p - hh * WID;
    float acc[3] = {bias[0], bias[1], bias[2]};

#pragma unroll
    for (int tap = 0; tap < 9; ++tap) {
        const int dh = tap / 3, dw = tap - dh * 3;
        const int gh = hh + dh - 1, gw = ww + dw - 1;
        if (gh < 0 || gh >= HGT || gw < 0 || gw >= WID) continue;
        const uint4* xp = (const uint4*)(in + ((long)b * HWPX + gh * WID + gw) * 32);
        float xx[32];
#pragma unroll
        for (int q = 0; q < 4; ++q) {
            uint4 v = xp[q];
            xx[q * 8 + 0] = bf2f_lo(v.x); xx[q * 8 + 1] = bf2f_hi(v.x);
            xx[q * 8 + 2] = bf2f_lo(v.y); xx[q * 8 + 3] = bf2f_hi(v.y);
            xx[q * 8 + 4] = bf2f_lo(v.z); xx[q * 8 + 5] = bf2f_hi(v.z);
            xx[q * 8 + 6] = bf2f_lo(v.w); xx[q * 8 + 7] = bf2f_hi(v.w);
        }
#pragma unroll
        for (int o = 0; o < 3; ++o)
#pragma unroll
            for (int ci = 0; ci < 32; ++ci)
                acc[o] += xx[ci] * wgt[o * 288 + ci * 9 + tap];
    }
#pragma unroll
    for (int o = 0; o < 3; ++o)
        outp[(long)(b * 3 + o) * HWPX + p] = acc[o] + img[(long)(b * 3 + o) * HWPX + p];
}

// ---------------------------------------------------------------------------
extern "C" void kernel_launch(void* const* d_in, const int* in_sizes, int n_in,
                              void* d_out, int out_size, void* d_ws, size_t ws_size,
                              hipStream_t stream)
{
    const int*   tokens  = (const int*)d_in[0];
    const float* img     = (const float*)d_in[1];
    const float* recon   = (const float*)d_in[2];
    const float* emb     = (const float*)d_in[3];
    const float* agg_w1  = (const float*)d_in[4];
    const float* agg_b1  = (const float*)d_in[5];
    const float* agg_w2  = (const float*)d_in[6];
    const float* agg_b2  = (const float*)d_in[7];
    const float* lut_w1  = (const float*)d_in[8];
    const float* lut_b1  = (const float*)d_in[9];
    const float* lut_w2  = (const float*)d_in[10];
    const float* lut_b2  = (const float*)d_in[11];
    const float* wg_w1   = (const float*)d_in[12];
    const float* wg_b1   = (const float*)d_in[13];
    const float* wg_w2   = (const float*)d_in[14];
    const float* wg_b2   = (const float*)d_in[15];
    const float* rp_cin_w = (const float*)d_in[16];
    const float* rp_cin_b = (const float*)d_in[17];
    const float* rp_rbA_w = (const float*)d_in[18];
    const float* rp_rbA_b = (const float*)d_in[19];
    const float* rp_rbA_g = (const float*)d_in[20];
    const float* rp_rbA_bt= (const float*)d_in[21];
    const float* rp_rbB_w = (const float*)d_in[22];
    const float* rp_rbB_b = (const float*)d_in[23];
    const float* rp_rbB_g = (const float*)d_in[24];
    const float* rp_rbB_bt= (const float*)d_in[25];
    const float* rp_cout_w= (const float*)d_in[26];
    const float* rp_cout_b= (const float*)d_in[27];
    const float* fu_cin_w = (const float*)d_in[28];
    const float* fu_cin_b = (const float*)d_in[29];
    const float* fu_rbA_w = (const float*)d_in[30];
    const float* fu_rbA_b = (const float*)d_in[31];
    const float* fu_rbA_g = (const float*)d_in[32];
    const float* fu_rbA_bt= (const float*)d_in[33];
    const float* fu_rbB_w = (const float*)d_in[34];
    const float* fu_rbB_b = (const float*)d_in[35];
    const float* fu_rbB_g = (const float*)d_in[36];
    const float* fu_rbB_bt= (const float*)d_in[37];
    const float* fu_cout_w= (const float*)d_in[38];
    const float* fu_cout_b= (const float*)d_in[39];

    float* ws = (float*)d_ws;
    float*  h3      = ws;                       // 1024
    float*  lwv     = ws + 1024;                // 32
    float*  partial = ws + 2048;                // 65536
    float*  clut    = ws + 69632;               // 431244
    ushort* wpack   = (ushort*)(ws + 524288);   // 4*9216 ushorts
    ushort* comb    = (ushort*)(ws + 589824);   // 4*HWPX*8 ushorts (bf16)
    ushort* act0    = (ushort*)(ws + 3145728);  // 18874368 ushorts
    ushort* act1    = (ushort*)(ws + 12582912);
    ushort* act2    = (ushort*)(ws + 22020096);
    float*  outp    = (float*)d_out;

    // pack conv32 A-fragments once (layers: rpA, rpB, fuA, fuB)
    pack_wconv_kernel<<<dim3(4), dim3(256), 0, stream>>>(
        rp_rbA_w, rp_rbB_w, fu_rbA_w, fu_rbB_w, wpack);

    // token head
    emb_partial_kernel<<<dim3(64, BB), dim3(256), 0, stream>>>(tokens, emb, partial);
    mlp_head_kernel<<<dim3(BB), dim3(1024), 0, stream>>>(
        partial, agg_w1, agg_b1, agg_w2, agg_b2,
        lut_w1, lut_b1, wg_w1, wg_b1, wg_w2, wg_b2, h3, lwv);

    // fused LUT GEMM + combine -> clut
    lut_fused_kernel<<<dim3((3 * G3 + 255) / 256), dim3(256), 0, stream>>>(
        h3, lwv, lut_w2, lut_b2, clut);

    const dim3 g1(HWPX / 256, BB), g2(HWPX / 512, BB), blk(256);
    const dim3 gm(NBLK), bm(512);

    // proc branch: img -> act0 -> act1 -> act2
    conv_in3_kernel<<<g2, blk, 0, stream>>>(img, rp_cin_w, rp_cin_b, act0);
    conv32_mfma<false><<<gm, bm, 0, stream>>>(
        act0, nullptr, wpack + 0 * 9216, rp_rbA_b, rp_rbA_g, rp_rbA_bt, act1);
    conv32_mfma<true><<<gm, bm, 0, stream>>>(
        act1, act0, wpack + 1 * 9216, rp_rbB_b, rp_rbB_g, rp_rbB_bt, act2);

    // merged: LUT apply + proc 32->3 -> comb (bf16)
    applylut_out3_kernel<<<g1, blk, 0, stream>>>(
        clut, recon, act2, rp_cout_w, rp_cout_b, comb);

    // fuse branch: comb -> act0 -> act1 -> act2 -> d_out (+img)
    conv_in6_kernel<<<g1, blk, 0, stream>>>(comb, fu_cin_w, fu_cin_b, act0);
    conv32_mfma<false><<<gm, bm, 0, stream>>>(
        act0, nullptr, wpack + 2 * 9216, fu_rbA_b, fu_rbA_g, fu_rbA_bt, act1);
    conv32_mfma<true><<<gm, bm, 0, stream>>>(
        act1, act0, wpack + 3 * 9216, fu_rbB_b, fu_rbB_g, fu_rbB_bt, act2);
    conv_final_kernel<<<g1, blk, 0, stream>>>(act2, fu_cout_w, fu_cout_b, img, outp);
}

// Round 17
// 508.439 us; speedup vs baseline: 1.9483x; 1.0860x over previous
//
#include <hip/hip_runtime.h>
#include <hip/hip_bf16.h>
#include <math.h>

// Problem constants
#define BB    4
#define TT    1024
#define EE    256
#define HIDD  256
#define LLUT  8
#define HGT   384
#define WID   384
#define HWPX  147456      // 384*384
#define GSZ   33
#define G3    35937       // 33^3
#define NCOL  862488      // L*3*G3

typedef __attribute__((ext_vector_type(8))) short bf16x8;   // 8 bf16 = 4 VGPRs
typedef __attribute__((ext_vector_type(4))) float f32x4;

// fast gelu (tanh form): max abs dev from exact erf-gelu ~1e-3, threshold 2e-2
__device__ __forceinline__ float gelu_f(float x) {
    float s = 1.5957691216057308f * x * (1.0f + 0.044715f * x * x);
    float e = __expf(s);
    return x - x / (e + 1.0f);   // x*sigmoid(s); safe at +-inf
}

__device__ __forceinline__ ushort f2bf(float x) {
    uint u = __float_as_uint(x);
    return (ushort)((u + 0x7FFFu + ((u >> 16) & 1u)) >> 16);   // RNE
}
__device__ __forceinline__ uint pack2bf(float a, float b) {
    return (uint)f2bf(a) | ((uint)f2bf(b) << 16);
}
__device__ __forceinline__ float bf2f_lo(uint u) { return __uint_as_float(u << 16); }
__device__ __forceinline__ float bf2f_hi(uint u) { return __uint_as_float(u & 0xFFFF0000u); }

// conv32 tiling (shared by MFMA conv kernels)
#define TH2 8
#define TW2 64
#define NTX (WID / TW2)          // 6
#define NTY (HGT / TH2)          // 48
#define NBLK (NTX * NTY * BB)    // 1152
#define CHUNK (NBLK / 8)         // 144
#define HALO_H2 10
#define HALO_W2 66
#define CSTR 40   // padded ushort stride per pixel (80 B)

// ---------------------------------------------------------------------------
// K-1: pack MFMA A-fragment tables (lane-linear bf16):
//   layers 0-3: 32->32 convs (rpA, rpB, fuA, fuB), 9216 each
//   layers 4-5: 32->3 convs (rp_cout, fu_cout), 9216 each (rows>=3 zero)
//   layer 6:    6->32 conv (fu_cin), K=54 padded to 64, 2048 entries
// ---------------------------------------------------------------------------
__global__ __launch_bounds__(256) void pack_wconv_kernel(
    const float* __restrict__ w0, const float* __restrict__ w1,
    const float* __restrict__ w2, const float* __restrict__ w3,
    const float* __restrict__ c0w, const float* __restrict__ c1w,
    const float* __restrict__ w6, ushort* __restrict__ wpk)
{
    const int layer = blockIdx.x;
    if (layer < 6) {
        const float* w = (layer == 0) ? w0 : (layer == 1) ? w1 :
                         (layer == 2) ? w2 : (layer == 3) ? w3 :
                         (layer == 4) ? c0w : c1w;
        const bool small = (layer >= 4);
        ushort* dst = wpk + layer * 9216;
        for (int i = threadIdx.x; i < 9216; i += 256) {
            const int j    = i & 7;
            const int lane = (i >> 3) & 63;
            const int half = (i >> 9) & 1;
            const int tap  = i >> 10;
            const int co = half * 16 + (lane & 15);
            const int ci = (lane >> 4) * 8 + j;
            float v = 0.f;
            if (!small || co < 3) v = w[co * 288 + ci * 9 + tap];
            dst[i] = f2bf(v);
        }
    } else {
        // k = ks*32 + (lane>>4)*8 + j; (tap, ci) = (k/6, k%6); zero for k>=54
        ushort* dst = wpk + 6 * 9216;
        for (int i = threadIdx.x; i < 2048; i += 256) {
            const int j    = i & 7;
            const int lane = (i >> 3) & 63;
            const int half = (i >> 9) & 1;
            const int ks   = i >> 10;
            const int co = half * 16 + (lane & 15);
            const int k  = ks * 32 + (lane >> 4) * 8 + j;
            float v = 0.f;
            if (k < 54) { const int tap = k / 6, ci = k - 6 * tap;
                          v = w6[co * 54 + ci * 9 + tap]; }
            dst[i] = f2bf(v);
        }
    }
}

// ---------------------------------------------------------------------------
// K0: embedding-mean partial sums. grid (64, B).
// ---------------------------------------------------------------------------
__global__ __launch_bounds__(256) void emb_partial_kernel(
    const int* __restrict__ tokens, const float* __restrict__ emb,
    float* __restrict__ partial)
{
    const int s = blockIdx.x, b = blockIdx.y, tid = threadIdx.x;
    const int* tok = tokens + b * TT + s * 16;
    float acc = 0.f;
#pragma unroll
    for (int t = 0; t < 16; ++t) acc += emb[tok[t] * EE + tid];
    partial[(b * 64 + s) * EE + tid] = acc;
}

// ---------------------------------------------------------------------------
// K1: fused token head, latency-parallel.
// ---------------------------------------------------------------------------
__global__ __launch_bounds__(1024) void mlp_head_kernel(
    const float* __restrict__ partial,
    const float* __restrict__ aw1, const float* __restrict__ ab1,
    const float* __restrict__ aw2, const float* __restrict__ ab2,
    const float* __restrict__ lw1, const float* __restrict__ lb1,
    const float* __restrict__ gw1, const float* __restrict__ gb1,
    const float* __restrict__ gw2, const float* __restrict__ gb2,
    float* __restrict__ h3_out, float* __restrict__ lw_out)
{
    const int b = blockIdx.x;
    const int tid = threadIdx.x;
    const int o = tid & 255;
    const int q = tid >> 8;
    __shared__ float tf[256], h1[256], tf2s[256], h4[64], lg[8];
    __shared__ float red[4][256];

    {
        float acc = 0.f;
#pragma unroll
        for (int s = 0; s < 16; ++s)
            acc += partial[(b * 64 + q * 16 + s) * EE + o];
        red[q][o] = acc;
    }
    __syncthreads();
    if (tid < 256)
        tf[tid] = (red[0][tid] + red[1][tid] + red[2][tid] + red[3][tid]) * (1.0f / TT);
    __syncthreads();

    {
        float s = 0.f;
#pragma unroll 8
        for (int j = 0; j < 64; ++j) {
            const int k = (q << 6) + j;
            s += tf[k] * aw1[k * HIDD + o];
        }
        red[q][o] = s;
    }
    __syncthreads();
    if (tid < 256)
        h1[tid] = gelu_f(red[0][tid] + red[1][tid] + red[2][tid] + red[3][tid] + ab1[tid]);
    __syncthreads();

    {
        float s = 0.f;
#pragma unroll 8
        for (int j = 0; j < 64; ++j) {
            const int k = (q << 6) + j;
            s += h1[k] * aw2[k * HIDD + o];
        }
        red[q][o] = s;
    }
    __syncthreads();
    if (tid < 256)
        tf2s[tid] = red[0][tid] + red[1][tid] + red[2][tid] + red[3][tid] + ab2[tid];
    __syncthreads();

    {
        float s = 0.f;
#pragma unroll 8
        for (int j = 0; j < 64; ++j) {
            const int k = (q << 6) + j;
            s += tf2s[k] * lw1[k * HIDD + o];
        }
        red[q][o] = s;
    }
    __syncthreads();
    if (tid < 256)
        h3_out[b * HIDD + tid] =
            gelu_f(red[0][tid] + red[1][tid] + red[2][tid] + red[3][tid] + lb1[tid]);
    __syncthreads();

    {
        const int o64 = tid & 63, q16 = tid >> 6;
        float s = 0.f;
#pragma unroll
        for (int j = 0; j < 16; ++j) {
            const int k = q16 * 16 + j;
            s += tf2s[k] * gw1[k * 64 + o64];
        }
        ((float*)red)[q16 * 64 + o64] = s;
    }
    __syncthreads();
    if (tid < 64) {
        float s = gb1[tid];
#pragma unroll
        for (int r = 0; r < 16; ++r) s += ((float*)red)[r * 64 + tid];
        h4[tid] = gelu_f(s);
    }
    __syncthreads();

    if (tid < 8) {
        float s = gb2[tid];
#pragma unroll 8
        for (int k = 0; k < 64; ++k) s += h4[k] * gw2[k * LLUT + tid];
        lg[tid] = s;
    }
    __syncthreads();
    if (tid == 0) {
        float m = lg[0];
        for (int i = 1; i < LLUT; ++i) m = fmaxf(m, lg[i]);
        float ssum = 0.f, ex[LLUT];
        for (int i = 0; i < LLUT; ++i) { ex[i] = expf(lg[i] - m); ssum += ex[i]; }
        for (int i = 0; i < LLUT; ++i) lw_out[b * LLUT + i] = ex[i] / ssum;
    }
}

// ---------------------------------------------------------------------------
// K2: fused LUT-GEMM + softmax-combine -> clut (883 MB w2 stream).
// ---------------------------------------------------------------------------
__global__ __launch_bounds__(256) void lut_fused_kernel(
    const float* __restrict__ h3, const float* __restrict__ lwv,
    const float* __restrict__ w2, const float* __restrict__ b2,
    float* __restrict__ clut)
{
    __shared__ float h[BB * HIDD];
    __shared__ float lws[BB * LLUT];
    const int tid = threadIdx.x;
    for (int i = tid; i < BB * HIDD; i += 256) h[i] = h3[i];
    if (tid < BB * LLUT) lws[tid] = lwv[tid];
    __syncthreads();

    const int idx = blockIdx.x * 256 + tid;
    if (idx >= 3 * G3) return;
    const int c = idx / G3, v = idx - c * G3;

    float acc[BB][LLUT];
#pragma unroll
    for (int b = 0; b < BB; ++b)
#pragma unroll
        for (int l = 0; l < LLUT; ++l) acc[b][l] = 0.f;

    const float* wbase = w2 + (long)c * G3 + v;   // + l*3*G3 + k*NCOL
#pragma unroll 4
    for (int k = 0; k < HIDD; ++k) {
        const float* row = wbase + (long)k * NCOL;
        float wl[LLUT];
#pragma unroll
        for (int l = 0; l < LLUT; ++l) wl[l] = row[l * 3 * G3];
#pragma unroll
        for (int b = 0; b < BB; ++b) {
            const float hb = h[b * HIDD + k];
#pragma unroll
            for (int l = 0; l < LLUT; ++l) acc[b][l] += wl[l] * hb;
        }
    }

    float bb[LLUT];
#pragma unroll
    for (int l = 0; l < LLUT; ++l) bb[l] = b2[(long)(l * 3 + c) * G3 + v];

#pragma unroll
    for (int b = 0; b < BB; ++b) {
        float s = 0.f;
#pragma unroll
        for (int l = 0; l < LLUT; ++l) s += lws[b * LLUT + l] * (acc[b][l] + bb[l]);
        clut[(long)(b * 3 + c) * G3 + v] = s;
    }
}

// ---------------------------------------------------------------------------
// K4: trilinear LUT apply ONLY -> comb slots 0..3 (bf16). Slots 4..7 are
// written by conv_out3_mfma<false>.
// ---------------------------------------------------------------------------
__global__ __launch_bounds__(256) void applylut_kernel(
    const float* __restrict__ clut, const float* __restrict__ recon,
    ushort* __restrict__ comb)
{
    const int p = blockIdx.x * 256 + threadIdx.x;
    const int b = blockIdx.y;

    const float* rc = recon + (long)b * 3 * HWPX;
    float cr = fminf(fmaxf(rc[p] * 32.f, 0.f), 32.f);
    float cg = fminf(fmaxf(rc[HWPX + p] * 32.f, 0.f), 32.f);
    float cb = fminf(fmaxf(rc[2 * HWPX + p] * 32.f, 0.f), 32.f);
    float fr = fminf(floorf(cr), 31.f);
    float fg = fminf(floorf(cg), 31.f);
    float fb = fminf(floorf(cb), 31.f);
    float tr = cr - fr, tg = cg - fg, tb_ = cb - fb;
    int idx = (((int)fr * GSZ + (int)fg) * GSZ + (int)fb);
    float c[3];
#pragma unroll
    for (int ch = 0; ch < 3; ++ch) {
        const float* lut = clut + (long)(b * 3 + ch) * G3;
        float v000 = lut[idx],                  v001 = lut[idx + 1];
        float v010 = lut[idx + GSZ],            v011 = lut[idx + GSZ + 1];
        float v100 = lut[idx + GSZ * GSZ],      v101 = lut[idx + GSZ * GSZ + 1];
        float v110 = lut[idx + GSZ * GSZ + GSZ], v111 = lut[idx + GSZ * GSZ + GSZ + 1];
        float c00 = v000 + (v001 - v000) * tb_;
        float c01 = v010 + (v011 - v010) * tb_;
        float c10 = v100 + (v101 - v100) * tb_;
        float c11 = v110 + (v111 - v110) * tb_;
        float c0 = c00 + (c01 - c00) * tg;
        float c1 = c10 + (c11 - c10) * tg;
        c[ch] = c0 + (c1 - c0) * tr;
    }
    uint2 u;
    u.x = pack2bf(c[0], c[1]);
    u.y = pack2bf(c[2], 0.f);
    *(uint2*)(comb + ((long)b * HWPX + p) * 8) = u;
}

// ---------------------------------------------------------------------------
// K5: 3->32 conv (img fp32 NCHW -> act NHWC bf16), gelu. 2 px/thread.
// ---------------------------------------------------------------------------
__global__ __launch_bounds__(256) void conv_in3_kernel(
    const float* __restrict__ img, const float* __restrict__ wgt,
    const float* __restrict__ bias, ushort* __restrict__ out)
{
    const int tid = threadIdx.x;
    const int p0 = (blockIdx.x * 256 + tid) * 2;
    const int b = blockIdx.y;
    const int hh = p0 / WID, ww = p0 - hh * WID;

    float acc[32][2];
#pragma unroll
    for (int o = 0; o < 32; ++o) { float bv = bias[o]; acc[o][0] = bv; acc[o][1] = bv; }

    const bool wlo = (ww > 0), whi = (ww + 2 < WID);
#pragma unroll
    for (int ci = 0; ci < 3; ++ci) {
        const float* ip = img + (long)(b * 3 + ci) * HWPX;
        float x[3][4];
#pragma unroll
        for (int dh = 0; dh < 3; ++dh) {
            const int hs = hh + dh - 1;
            const bool hok = (hs >= 0) && (hs < HGT);
            const float* rp_ = ip + hs * WID + ww;
            x[dh][0] = (hok && wlo) ? rp_[-1] : 0.f;
            x[dh][1] = hok ? rp_[0] : 0.f;
            x[dh][2] = hok ? rp_[1] : 0.f;
            x[dh][3] = (hok && whi) ? rp_[2] : 0.f;
        }
#pragma unroll
        for (int o = 0; o < 32; ++o) {
            const float* wv = wgt + o * 27 + ci * 9;   // uniform -> s_load
#pragma unroll
            for (int dh = 0; dh < 3; ++dh)
#pragma unroll
                for (int dw = 0; dw < 3; ++dw) {
                    const float w = wv[dh * 3 + dw];
                    acc[o][0] += x[dh][dw]     * w;
                    acc[o][1] += x[dh][dw + 1] * w;
                }
        }
    }

    ushort* op = out + ((long)b * HWPX + p0) * 32;
#pragma unroll
    for (int px = 0; px < 2; ++px) {
        uint u[16];
#pragma unroll
        for (int o2 = 0; o2 < 16; ++o2)
            u[o2] = pack2bf(gelu_f(acc[2 * o2][px]), gelu_f(acc[2 * o2 + 1][px]));
        uint4* dst = (uint4*)(op + px * 32);
#pragma unroll
        for (int q = 0; q < 4; ++q)
            dst[q] = make_uint4(u[4 * q], u[4 * q + 1], u[4 * q + 2], u[4 * q + 3]);
    }
}

// ---------------------------------------------------------------------------
// K6: MFMA 32->32 conv (r14 measured-best structure).
// ---------------------------------------------------------------------------
template <bool HAS_RES>
__global__ __launch_bounds__(512, 6) void conv32_mfma(
    const ushort* __restrict__ in, const ushort* __restrict__ res,
    const ushort* __restrict__ wpk, const float* __restrict__ bias,
    const float* __restrict__ bn_g, const float* __restrict__ bn_bt,
    ushort* __restrict__ out)
{
    __shared__ ushort halo[HALO_H2 * HALO_W2 * CSTR];   // 52800 B
    __shared__ float s_scale[32], s_shift[32];

    const int tid = threadIdx.x;
    const int bid = blockIdx.x;
    const int t   = (bid & 7) * CHUNK + (bid >> 3);
    const int tx  = t % NTX;
    const int rem = t / NTX;
    const int ty  = rem % NTY;
    const int b   = rem / NTY;
    const int h0 = ty * TH2;
    const int w0 = tx * TW2;

    if (tid < 32) {
        float sg = bn_g[tid] * 0.9999950000375f;   // g*(1+1e-5)^-0.5
        s_scale[tid] = sg;
        s_shift[tid] = bias[tid] * sg + bn_bt[tid];
    }

    const ushort* inb = in + (long)b * HWPX * 32;
    for (int i = tid; i < HALO_H2 * HALO_W2 * 4; i += 512) {
        const int row = i / (HALO_W2 * 4);
        const int rem2 = i - row * (HALO_W2 * 4);
        const int px = rem2 >> 2, q = rem2 & 3;
        const int gh = h0 + row - 1, gw = w0 + px - 1;
        uint4 v = make_uint4(0u, 0u, 0u, 0u);
        if (gh >= 0 && gh < HGT && gw >= 0 && gw < WID)
            v = *(const uint4*)(inb + ((long)gh * WID + gw) * 32 + q * 8);
        *(uint4*)(&halo[(row * HALO_W2 + px) * CSTR + q * 8]) = v;
    }
    __syncthreads();

    const int lane = tid & 63, wid = tid >> 6;
    const int l15 = lane & 15, kg = lane >> 4;
    const int r = wid;
    const ushort* wlane = wpk + lane * 8;

    f32x4 acc[4][2];
#pragma unroll
    for (int f = 0; f < 4; ++f)
#pragma unroll
        for (int cf = 0; cf < 2; ++cf)
            acc[f][cf] = (f32x4){0.f, 0.f, 0.f, 0.f};

#pragma unroll
    for (int tap = 0; tap < 9; ++tap) {
        const int dh = tap / 3, dw = tap - dh * 3;
        const bf16x8 a0 = *(const bf16x8*)(wlane + (tap * 2 + 0) * 512);
        const bf16x8 a1 = *(const bf16x8*)(wlane + (tap * 2 + 1) * 512);
#pragma unroll
        for (int f = 0; f < 4; ++f) {
            const int c0 = f * 16;
            const bf16x8 bfv = *(const bf16x8*)(
                &halo[((r + dh) * HALO_W2 + (c0 + dw + l15)) * CSTR + kg * 8]);
            acc[f][0] = __builtin_amdgcn_mfma_f32_16x16x32_bf16(a0, bfv, acc[f][0], 0, 0, 0);
            acc[f][1] = __builtin_amdgcn_mfma_f32_16x16x32_bf16(a1, bfv, acc[f][1], 0, 0, 0);
        }
    }

#pragma unroll
    for (int f = 0; f < 4; ++f) {
        const int c0 = f * 16;
        const long gpx = (long)b * HWPX + (long)(h0 + r) * WID + (w0 + c0 + l15);
#pragma unroll
        for (int cf = 0; cf < 2; ++cf) {
            const int co0 = cf * 16 + kg * 4;
            const float4 sc = *(const float4*)(&s_scale[co0]);
            const float4 sh = *(const float4*)(&s_shift[co0]);
            float v0 = acc[f][cf][0] * sc.x + sh.x;
            float v1 = acc[f][cf][1] * sc.y + sh.y;
            float v2 = acc[f][cf][2] * sc.z + sh.z;
            float v3 = acc[f][cf][3] * sc.w + sh.w;
            if (HAS_RES) {
                const uint2 rv = *(const uint2*)(res + gpx * 32 + co0);
                v0 += bf2f_lo(rv.x); v1 += bf2f_hi(rv.x);
                v2 += bf2f_lo(rv.y); v3 += bf2f_hi(rv.y);
            }
            uint2 o;
            o.x = pack2bf(gelu_f(v0), gelu_f(v1));
            o.y = pack2bf(gelu_f(v2), gelu_f(v3));
            *(uint2*)(out + gpx * 32 + co0) = o;
        }
    }
}

// ---------------------------------------------------------------------------
// K7: MFMA 32->3 conv. Same halo/B-frags as conv32; A = zero-padded 3-row
// table (half0 only); 36 MFMA/wave; lanes kg==0 hold rows 0..3 of D.
// FINAL=false: write comb slots 4..7 (bf16).  FINAL=true: +img -> fp32 NCHW.
// ---------------------------------------------------------------------------
template <bool FINAL>
__global__ __launch_bounds__(512, 4) void conv_out3_mfma(
    const ushort* __restrict__ in, const ushort* __restrict__ wpk,
    const float* __restrict__ bias, const float* __restrict__ img,
    float* __restrict__ outp, ushort* __restrict__ comb)
{
    __shared__ ushort halo[HALO_H2 * HALO_W2 * CSTR];   // 52800 B

    const int tid = threadIdx.x;
    const int bid = blockIdx.x;
    const int t   = (bid & 7) * CHUNK + (bid >> 3);
    const int tx  = t % NTX;
    const int rem = t / NTX;
    const int ty  = rem % NTY;
    const int b   = rem / NTY;
    const int h0 = ty * TH2;
    const int w0 = tx * TW2;

    const ushort* inb = in + (long)b * HWPX * 32;
    for (int i = tid; i < HALO_H2 * HALO_W2 * 4; i += 512) {
        const int row = i / (HALO_W2 * 4);
        const int rem2 = i - row * (HALO_W2 * 4);
        const int px = rem2 >> 2, q = rem2 & 3;
        const int gh = h0 + row - 1, gw = w0 + px - 1;
        uint4 v = make_uint4(0u, 0u, 0u, 0u);
        if (gh >= 0 && gh < HGT && gw >= 0 && gw < WID)
            v = *(const uint4*)(inb + ((long)gh * WID + gw) * 32 + q * 8);
        *(uint4*)(&halo[(row * HALO_W2 + px) * CSTR + q * 8]) = v;
    }
    __syncthreads();

    const int lane = tid & 63, wid = tid >> 6;
    const int l15 = lane & 15, kg = lane >> 4;
    const int r = wid;
    const ushort* wlane = wpk + lane * 8;

    f32x4 acc[4];
#pragma unroll
    for (int f = 0; f < 4; ++f) acc[f] = (f32x4){0.f, 0.f, 0.f, 0.f};

#pragma unroll
    for (int tap = 0; tap < 9; ++tap) {
        const int dh = tap / 3, dw = tap - dh * 3;
        const bf16x8 a0 = *(const bf16x8*)(wlane + (tap * 2 + 0) * 512);
#pragma unroll
        for (int f = 0; f < 4; ++f) {
            const int c0 = f * 16;
            const bf16x8 bfv = *(const bf16x8*)(
                &halo[((r + dh) * HALO_W2 + (c0 + dw + l15)) * CSTR + kg * 8]);
            acc[f] = __builtin_amdgcn_mfma_f32_16x16x32_bf16(a0, bfv, acc[f], 0, 0, 0);
        }
    }

    if (kg == 0) {   // rows 0..3 of D live in kg==0 lanes; rows 0..2 valid
        const float b0 = bias[0], b1 = bias[1], b2v = bias[2];
#pragma unroll
        for (int f = 0; f < 4; ++f) {
            const int p = (h0 + r) * WID + (w0 + f * 16 + l15);
            const long gpx = (long)b * HWPX + p;
            float v0 = acc[f][0] + b0;
            float v1 = acc[f][1] + b1;
            float v2 = acc[f][2] + b2v;
            if (FINAL) {
                outp[(long)(b * 3 + 0) * HWPX + p] = v0 + img[(long)(b * 3 + 0) * HWPX + p];
                outp[(long)(b * 3 + 1) * HWPX + p] = v1 + img[(long)(b * 3 + 1) * HWPX + p];
                outp[(long)(b * 3 + 2) * HWPX + p] = v2 + img[(long)(b * 3 + 2) * HWPX + p];
            } else {
                uint2 u;
                u.x = pack2bf(v0, v1);
                u.y = pack2bf(v2, 0.f);
                *(uint2*)(comb + gpx * 8 + 4) = u;
            }
        }
    }
}

// ---------------------------------------------------------------------------
// K8: MFMA 6->32 conv (comb bf16 [px][8] -> act NHWC bf16), gelu.
// K=54 padded to 64, k=(tap*6+ci) shared between A table and B gather.
// Tiny comb halo in LDS (10.5 KB). 16 MFMA/wave.
// ---------------------------------------------------------------------------
__global__ __launch_bounds__(512) void conv_in6_mfma(
    const ushort* __restrict__ comb, const ushort* __restrict__ wpk6,
    const float* __restrict__ bias, ushort* __restrict__ out)
{
    __shared__ ushort chalo[HALO_H2 * HALO_W2 * 8];   // 10560 B
    __shared__ float s_bias[32];

    const int tid = threadIdx.x;
    const int bid = blockIdx.x;
    const int t   = (bid & 7) * CHUNK + (bid >> 3);
    const int tx  = t % NTX;
    const int rem = t / NTX;
    const int ty  = rem % NTY;
    const int b   = rem / NTY;
    const int h0 = ty * TH2;
    const int w0 = tx * TW2;

    if (tid < 32) s_bias[tid] = bias[tid];

    const ushort* cb = comb + (long)b * HWPX * 8;
    for (int i = tid; i < HALO_H2 * HALO_W2; i += 512) {
        const int row = i / HALO_W2, px = i - row * HALO_W2;
        const int gh = h0 + row - 1, gw = w0 + px - 1;
        uint4 v = make_uint4(0u, 0u, 0u, 0u);
        if (gh >= 0 && gh < HGT && gw >= 0 && gw < WID)
            v = *(const uint4*)(cb + ((long)gh * WID + gw) * 8);
        *(uint4*)(&chalo[i * 8]) = v;
    }
    __syncthreads();

    const int lane = tid & 63, wid = tid >> 6;
    const int l15 = lane & 15, kg = lane >> 4;
    const int r = wid;
    const ushort* wl6 = wpk6 + lane * 8;

    f32x4 acc[4][2];
#pragma unroll
    for (int f = 0; f < 4; ++f)
#pragma unroll
        for (int cf = 0; cf < 2; ++cf)
            acc[f][cf] = (f32x4){0.f, 0.f, 0.f, 0.f};

#pragma unroll
    for (int ks = 0; ks < 2; ++ks) {
        const bf16x8 a0 = *(const bf16x8*)(wl6 + (ks * 2 + 0) * 512);
        const bf16x8 a1 = *(const bf16x8*)(wl6 + (ks * 2 + 1) * 512);
#pragma unroll
        for (int f = 0; f < 4; ++f) {
            const int c0 = f * 16;
            bf16x8 bv;
#pragma unroll
            for (int j = 0; j < 8; ++j) {
                const int k = ks * 32 + kg * 8 + j;
                ushort val = 0;
                if (k < 54) {
                    const int tap = k / 6, ci = k - 6 * tap;
                    const int dh = tap / 3, dwp = tap - 3 * dh;
                    const int slot = ci + (ci >= 3 ? 1 : 0);
                    val = chalo[((r + dh) * HALO_W2 + (c0 + dwp + l15)) * 8 + slot];
                }
                bv[j] = (short)val;
            }
            acc[f][0] = __builtin_amdgcn_mfma_f32_16x16x32_bf16(a0, bv, acc[f][0], 0, 0, 0);
            acc[f][1] = __builtin_amdgcn_mfma_f32_16x16x32_bf16(a1, bv, acc[f][1], 0, 0, 0);
        }
    }

#pragma unroll
    for (int f = 0; f < 4; ++f) {
        const int c0 = f * 16;
        const long gpx = (long)b * HWPX + (long)(h0 + r) * WID + (w0 + c0 + l15);
#pragma unroll
        for (int cf = 0; cf < 2; ++cf) {
            const int co0 = cf * 16 + kg * 4;
            const float4 bv4 = *(const float4*)(&s_bias[co0]);
            float v0 = acc[f][cf][0] + bv4.x;
            float v1 = acc[f][cf][1] + bv4.y;
            float v2 = acc[f][cf][2] + bv4.z;
            float v3 = acc[f][cf][3] + bv4.w;
            uint2 o;
            o.x = pack2bf(gelu_f(v0), gelu_f(v1));
            o.y = pack2bf(gelu_f(v2), gelu_f(v3));
            *(uint2*)(out + gpx * 32 + co0) = o;
        }
    }
}

// ---------------------------------------------------------------------------
extern "C" void kernel_launch(void* const* d_in, const int* in_sizes, int n_in,
                              void* d_out, int out_size, void* d_ws, size_t ws_size,
                              hipStream_t stream)
{
    const int*   tokens  = (const int*)d_in[0];
    const float* img     = (const float*)d_in[1];
    const float* recon   = (const float*)d_in[2];
    const float* emb     = (const float*)d_in[3];
    const float* agg_w1  = (const float*)d_in[4];
    const float* agg_b1  = (const float*)d_in[5];
    const float* agg_w2  = (const float*)d_in[6];
    const float* agg_b2  = (const float*)d_in[7];
    const float* lut_w1  = (const float*)d_in[8];
    const float* lut_b1  = (const float*)d_in[9];
    const float* lut_w2  = (const float*)d_in[10];
    const float* lut_b2  = (const float*)d_in[11];
    const float* wg_w1   = (const float*)d_in[12];
    const float* wg_b1   = (const float*)d_in[13];
    const float* wg_w2   = (const float*)d_in[14];
    const float* wg_b2   = (const float*)d_in[15];
    const float* rp_cin_w = (const float*)d_in[16];
    const float* rp_cin_b = (const float*)d_in[17];
    const float* rp_rbA_w = (const float*)d_in[18];
    const float* rp_rbA_b = (const float*)d_in[19];
    const float* rp_rbA_g = (const float*)d_in[20];
    const float* rp_rbA_bt= (const float*)d_in[21];
    const float* rp_rbB_w = (const float*)d_in[22];
    const float* rp_rbB_b = (const float*)d_in[23];
    const float* rp_rbB_g = (const float*)d_in[24];
    const float* rp_rbB_bt= (const float*)d_in[25];
    const float* rp_cout_w= (const float*)d_in[26];
    const float* rp_cout_b= (const float*)d_in[27];
    const float* fu_cin_w = (const float*)d_in[28];
    const float* fu_cin_b = (const float*)d_in[29];
    const float* fu_rbA_w = (const float*)d_in[30];
    const float* fu_rbA_b = (const float*)d_in[31];
    const float* fu_rbA_g = (const float*)d_in[32];
    const float* fu_rbA_bt= (const float*)d_in[33];
    const float* fu_rbB_w = (const float*)d_in[34];
    const float* fu_rbB_b = (const float*)d_in[35];
    const float* fu_rbB_g = (const float*)d_in[36];
    const float* fu_rbB_bt= (const float*)d_in[37];
    const float* fu_cout_w= (const float*)d_in[38];
    const float* fu_cout_b= (const float*)d_in[39];

    float* ws = (float*)d_ws;
    float*  h3      = ws;                       // 1024
    float*  lwv     = ws + 1024;                // 32
    float*  partial = ws + 2048;                // 65536
    float*  clut    = ws + 69632;               // 431244
    ushort* wpack   = (ushort*)(ws + 524288);   // 6*9216+2048 = 57344 ushorts
    ushort* comb    = (ushort*)(ws + 589824);   // 4*HWPX*8 ushorts (bf16)
    ushort* act0    = (ushort*)(ws + 3145728);  // 18874368 ushorts
    ushort* act1    = (ushort*)(ws + 12582912);
    ushort* act2    = (ushort*)(ws + 22020096);
    float*  outp    = (float*)d_out;

    // pack all MFMA A-fragment tables
    pack_wconv_kernel<<<dim3(7), dim3(256), 0, stream>>>(
        rp_rbA_w, rp_rbB_w, fu_rbA_w, fu_rbB_w, rp_cout_w, fu_cout_w,
        fu_cin_w, wpack);

    // token head
    emb_partial_kernel<<<dim3(64, BB), dim3(256), 0, stream>>>(tokens, emb, partial);
    mlp_head_kernel<<<dim3(BB), dim3(1024), 0, stream>>>(
        partial, agg_w1, agg_b1, agg_w2, agg_b2,
        lut_w1, lut_b1, wg_w1, wg_b1, wg_w2, wg_b2, h3, lwv);

    // fused LUT GEMM + combine -> clut
    lut_fused_kernel<<<dim3((3 * G3 + 255) / 256), dim3(256), 0, stream>>>(
        h3, lwv, lut_w2, lut_b2, clut);

    const dim3 g1(HWPX / 256, BB), g2(HWPX / 512, BB), blk(256);
    const dim3 gm(NBLK), bm(512);

    // proc branch: img -> act0 -> act1 -> act2
    conv_in3_kernel<<<g2, blk, 0, stream>>>(img, rp_cin_w, rp_cin_b, act0);
    conv32_mfma<false><<<gm, bm, 0, stream>>>(
        act0, nullptr, wpack + 0 * 9216, rp_rbA_b, rp_rbA_g, rp_rbA_bt, act1);
    conv32_mfma<true><<<gm, bm, 0, stream>>>(
        act1, act0, wpack + 1 * 9216, rp_rbB_b, rp_rbB_g, rp_rbB_bt, act2);

    // LUT apply -> comb lo; proc 32->3 (MFMA) -> comb hi
    applylut_kernel<<<g1, blk, 0, stream>>>(clut, recon, comb);
    conv_out3_mfma<false><<<gm, bm, 0, stream>>>(
        act2, wpack + 4 * 9216, rp_cout_b, nullptr, nullptr, comb);

    // fuse branch: comb -> act0 -> act1 -> act2 -> d_out (+img)
    conv_in6_mfma<<<gm, bm, 0, stream>>>(comb, wpack + 6 * 9216, fu_cin_b, act0);
    conv32_mfma<false><<<gm, bm, 0, stream>>>(
        act0, nullptr, wpack + 2 * 9216, fu_rbA_b, fu_rbA_g, fu_rbA_bt, act1);
    conv32_mfma<true><<<gm, bm, 0, stream>>>(
        act1, act0, wpack + 3 * 9216, fu_rbB_b, fu_rbB_g, fu_rbB_bt, act2);
    conv_out3_mfma<true><<<gm, bm, 0, stream>>>(
        act2, wpack + 5 * 9216, fu_cout_b, img, outp, nullptr);
}

// Round 18
// 476.368 us; speedup vs baseline: 2.0795x; 1.0673x over previous
//
#include <hip/hip_runtime.h>
#include <hip/hip_bf16.h>
#include <math.h>

// Problem constants
#define BB    4
#define TT    1024
#define EE    256
#define HIDD  256
#define LLUT  8
#define HGT   384
#define WID   384
#define HWPX  147456      // 384*384
#define GSZ   33
#define G3    35937       // 33^3
#define NCOL  862488      // L*3*G3

typedef __attribute__((ext_vector_type(8))) short bf16x8;   // 8 bf16 = 4 VGPRs
typedef __attribute__((ext_vector_type(4))) float f32x4;

// fast gelu (tanh form): max abs dev from exact erf-gelu ~1e-3, threshold 2e-2
__device__ __forceinline__ float gelu_f(float x) {
    float s = 1.5957691216057308f * x * (1.0f + 0.044715f * x * x);
    float e = __expf(s);
    return x - x / (e + 1.0f);   // x*sigmoid(s); safe at +-inf
}

__device__ __forceinline__ ushort f2bf(float x) {
    uint u = __float_as_uint(x);
    return (ushort)((u + 0x7FFFu + ((u >> 16) & 1u)) >> 16);   // RNE
}
__device__ __forceinline__ uint pack2bf(float a, float b) {
    return (uint)f2bf(a) | ((uint)f2bf(b) << 16);
}
__device__ __forceinline__ float bf2f_lo(uint u) { return __uint_as_float(u << 16); }
__device__ __forceinline__ float bf2f_hi(uint u) { return __uint_as_float(u & 0xFFFF0000u); }

// conv tiling (shared by MFMA conv kernels)
#define TH2 8
#define TW2 64
#define NTX (WID / TW2)          // 6
#define NTY (HGT / TH2)          // 48
#define NBLK (NTX * NTY * BB)    // 1152
#define CHUNK (NBLK / 8)         // 144
#define HALO_H2 10
#define HALO_W2 66
#define CSTR 40   // padded ushort stride per pixel (80 B)

// wpack layout (ushorts):
//   0..4*9216   : 32->32 convs (rpA, rpB, fuA, fuB)
//   4*9216..6*9216 : 32->3 convs (rp_cout, fu_cout), rows>=3 zero
//   55296..57344   : 6->32 conv (fu_cin), K=54 pad 64
//   57344..58368   : 3->32 conv (rp_cin), K=27 pad 32
#define WPK_IN6 55296
#define WPK_IN3 57344

// ---------------------------------------------------------------------------
// K-1: pack MFMA A-fragment tables (lane-linear bf16).
// ---------------------------------------------------------------------------
__global__ __launch_bounds__(256) void pack_wconv_kernel(
    const float* __restrict__ w0, const float* __restrict__ w1,
    const float* __restrict__ w2, const float* __restrict__ w3,
    const float* __restrict__ c0w, const float* __restrict__ c1w,
    const float* __restrict__ w6, const float* __restrict__ w7,
    ushort* __restrict__ wpk)
{
    const int layer = blockIdx.x;
    if (layer < 6) {
        const float* w = (layer == 0) ? w0 : (layer == 1) ? w1 :
                         (layer == 2) ? w2 : (layer == 3) ? w3 :
                         (layer == 4) ? c0w : c1w;
        const bool small = (layer >= 4);
        ushort* dst = wpk + layer * 9216;
        for (int i = threadIdx.x; i < 9216; i += 256) {
            const int j    = i & 7;
            const int lane = (i >> 3) & 63;
            const int half = (i >> 9) & 1;
            const int tap  = i >> 10;
            const int co = half * 16 + (lane & 15);
            const int ci = (lane >> 4) * 8 + j;
            float v = 0.f;
            if (!small || co < 3) v = w[co * 288 + ci * 9 + tap];
            dst[i] = f2bf(v);
        }
    } else if (layer == 6) {
        // in6: k = ks*32 + (lane>>4)*8 + j; (tap, ci) = (k/6, k%6); 0 for k>=54
        ushort* dst = wpk + WPK_IN6;
        for (int i = threadIdx.x; i < 2048; i += 256) {
            const int j    = i & 7;
            const int lane = (i >> 3) & 63;
            const int half = (i >> 9) & 1;
            const int ks   = i >> 10;
            const int co = half * 16 + (lane & 15);
            const int k  = ks * 32 + (lane >> 4) * 8 + j;
            float v = 0.f;
            if (k < 54) { const int tap = k / 6, ci = k - 6 * tap;
                          v = w6[co * 54 + ci * 9 + tap]; }
            dst[i] = f2bf(v);
        }
    } else {
        // in3: k = (lane>>4)*8 + j; (tap, ci) = (k/3, k%3); 0 for k>=27
        ushort* dst = wpk + WPK_IN3;
        for (int i = threadIdx.x; i < 1024; i += 256) {
            const int j    = i & 7;
            const int lane = (i >> 3) & 63;
            const int half = (i >> 9) & 1;
            const int co = half * 16 + (lane & 15);
            const int k  = (lane >> 4) * 8 + j;
            float v = 0.f;
            if (k < 27) { const int tap = k / 3, ci = k - 3 * tap;
                          v = w7[co * 27 + ci * 9 + tap]; }
            dst[i] = f2bf(v);
        }
    }
}

// ---------------------------------------------------------------------------
// K0: embedding-mean partial sums. grid (64, B).
// ---------------------------------------------------------------------------
__global__ __launch_bounds__(256) void emb_partial_kernel(
    const int* __restrict__ tokens, const float* __restrict__ emb,
    float* __restrict__ partial)
{
    const int s = blockIdx.x, b = blockIdx.y, tid = threadIdx.x;
    const int* tok = tokens + b * TT + s * 16;
    float acc = 0.f;
#pragma unroll
    for (int t = 0; t < 16; ++t) acc += emb[tok[t] * EE + tid];
    partial[(b * 64 + s) * EE + tid] = acc;
}

// ---------------------------------------------------------------------------
// K1: fused token head, latency-parallel.
// ---------------------------------------------------------------------------
__global__ __launch_bounds__(1024) void mlp_head_kernel(
    const float* __restrict__ partial,
    const float* __restrict__ aw1, const float* __restrict__ ab1,
    const float* __restrict__ aw2, const float* __restrict__ ab2,
    const float* __restrict__ lw1, const float* __restrict__ lb1,
    const float* __restrict__ gw1, const float* __restrict__ gb1,
    const float* __restrict__ gw2, const float* __restrict__ gb2,
    float* __restrict__ h3_out, float* __restrict__ lw_out)
{
    const int b = blockIdx.x;
    const int tid = threadIdx.x;
    const int o = tid & 255;
    const int q = tid >> 8;
    __shared__ float tf[256], h1[256], tf2s[256], h4[64], lg[8];
    __shared__ float red[4][256];

    {
        float acc = 0.f;
#pragma unroll
        for (int s = 0; s < 16; ++s)
            acc += partial[(b * 64 + q * 16 + s) * EE + o];
        red[q][o] = acc;
    }
    __syncthreads();
    if (tid < 256)
        tf[tid] = (red[0][tid] + red[1][tid] + red[2][tid] + red[3][tid]) * (1.0f / TT);
    __syncthreads();

    {
        float s = 0.f;
#pragma unroll 8
        for (int j = 0; j < 64; ++j) {
            const int k = (q << 6) + j;
            s += tf[k] * aw1[k * HIDD + o];
        }
        red[q][o] = s;
    }
    __syncthreads();
    if (tid < 256)
        h1[tid] = gelu_f(red[0][tid] + red[1][tid] + red[2][tid] + red[3][tid] + ab1[tid]);
    __syncthreads();

    {
        float s = 0.f;
#pragma unroll 8
        for (int j = 0; j < 64; ++j) {
            const int k = (q << 6) + j;
            s += h1[k] * aw2[k * HIDD + o];
        }
        red[q][o] = s;
    }
    __syncthreads();
    if (tid < 256)
        tf2s[tid] = red[0][tid] + red[1][tid] + red[2][tid] + red[3][tid] + ab2[tid];
    __syncthreads();

    {
        float s = 0.f;
#pragma unroll 8
        for (int j = 0; j < 64; ++j) {
            const int k = (q << 6) + j;
            s += tf2s[k] * lw1[k * HIDD + o];
        }
        red[q][o] = s;
    }
    __syncthreads();
    if (tid < 256)
        h3_out[b * HIDD + tid] =
            gelu_f(red[0][tid] + red[1][tid] + red[2][tid] + red[3][tid] + lb1[tid]);
    __syncthreads();

    {
        const int o64 = tid & 63, q16 = tid >> 6;
        float s = 0.f;
#pragma unroll
        for (int j = 0; j < 16; ++j) {
            const int k = q16 * 16 + j;
            s += tf2s[k] * gw1[k * 64 + o64];
        }
        ((float*)red)[q16 * 64 + o64] = s;
    }
    __syncthreads();
    if (tid < 64) {
        float s = gb1[tid];
#pragma unroll
        for (int r = 0; r < 16; ++r) s += ((float*)red)[r * 64 + tid];
        h4[tid] = gelu_f(s);
    }
    __syncthreads();

    if (tid < 8) {
        float s = gb2[tid];
#pragma unroll 8
        for (int k = 0; k < 64; ++k) s += h4[k] * gw2[k * LLUT + tid];
        lg[tid] = s;
    }
    __syncthreads();
    if (tid == 0) {
        float m = lg[0];
        for (int i = 1; i < LLUT; ++i) m = fmaxf(m, lg[i]);
        float ssum = 0.f, ex[LLUT];
        for (int i = 0; i < LLUT; ++i) { ex[i] = expf(lg[i] - m); ssum += ex[i]; }
        for (int i = 0; i < LLUT; ++i) lw_out[b * LLUT + i] = ex[i] / ssum;
    }
}

// ---------------------------------------------------------------------------
// K2: fused LUT-GEMM + softmax-combine -> clut (883 MB w2 stream).
// ---------------------------------------------------------------------------
__global__ __launch_bounds__(256) void lut_fused_kernel(
    const float* __restrict__ h3, const float* __restrict__ lwv,
    const float* __restrict__ w2, const float* __restrict__ b2,
    float* __restrict__ clut)
{
    __shared__ float h[BB * HIDD];
    __shared__ float lws[BB * LLUT];
    const int tid = threadIdx.x;
    for (int i = tid; i < BB * HIDD; i += 256) h[i] = h3[i];
    if (tid < BB * LLUT) lws[tid] = lwv[tid];
    __syncthreads();

    const int idx = blockIdx.x * 256 + tid;
    if (idx >= 3 * G3) return;
    const int c = idx / G3, v = idx - c * G3;

    float acc[BB][LLUT];
#pragma unroll
    for (int b = 0; b < BB; ++b)
#pragma unroll
        for (int l = 0; l < LLUT; ++l) acc[b][l] = 0.f;

    const float* wbase = w2 + (long)c * G3 + v;   // + l*3*G3 + k*NCOL
#pragma unroll 4
    for (int k = 0; k < HIDD; ++k) {
        const float* row = wbase + (long)k * NCOL;
        float wl[LLUT];
#pragma unroll
        for (int l = 0; l < LLUT; ++l) wl[l] = row[l * 3 * G3];
#pragma unroll
        for (int b = 0; b < BB; ++b) {
            const float hb = h[b * HIDD + k];
#pragma unroll
            for (int l = 0; l < LLUT; ++l) acc[b][l] += wl[l] * hb;
        }
    }

    float bb[LLUT];
#pragma unroll
    for (int l = 0; l < LLUT; ++l) bb[l] = b2[(long)(l * 3 + c) * G3 + v];

#pragma unroll
    for (int b = 0; b < BB; ++b) {
        float s = 0.f;
#pragma unroll
        for (int l = 0; l < LLUT; ++l) s += lws[b * LLUT + l] * (acc[b][l] + bb[l]);
        clut[(long)(b * 3 + c) * G3 + v] = s;
    }
}

// ---------------------------------------------------------------------------
// K5: MFMA 3->32 conv (img fp32 NCHW -> act NHWC bf16), gelu.
// K=27 padded to 32, k=(tap*3+ci). img halo staged as bf16 [10][66][4] LDS.
// ---------------------------------------------------------------------------
__global__ __launch_bounds__(512) void conv_in3_mfma(
    const float* __restrict__ img, const ushort* __restrict__ wpk3,
    const float* __restrict__ bias, ushort* __restrict__ out)
{
    __shared__ ushort ihalo[HALO_H2 * HALO_W2 * 4];   // 5280 B
    __shared__ float s_bias[32];

    const int tid = threadIdx.x;
    const int bid = blockIdx.x;
    const int t   = (bid & 7) * CHUNK + (bid >> 3);
    const int tx  = t % NTX;
    const int rem = t / NTX;
    const int ty  = rem % NTY;
    const int b   = rem / NTY;
    const int h0 = ty * TH2;
    const int w0 = tx * TW2;

    if (tid < 32) s_bias[tid] = bias[tid];

    const float* imb = img + (long)b * 3 * HWPX;
    for (int i = tid; i < HALO_H2 * HALO_W2; i += 512) {
        const int row = i / HALO_W2, px = i - row * HALO_W2;
        const int gh = h0 + row - 1, gw = w0 + px - 1;
        float c0v = 0.f, c1v = 0.f, c2v = 0.f;
        if (gh >= 0 && gh < HGT && gw >= 0 && gw < WID) {
            const int p = gh * WID + gw;
            c0v = imb[p]; c1v = imb[HWPX + p]; c2v = imb[2 * HWPX + p];
        }
        uint2 u; u.x = pack2bf(c0v, c1v); u.y = pack2bf(c2v, 0.f);
        *(uint2*)(&ihalo[i * 4]) = u;
    }
    __syncthreads();

    const int lane = tid & 63, wid = tid >> 6;
    const int l15 = lane & 15, kg = lane >> 4;
    const int r = wid;
    const ushort* wl3 = wpk3 + lane * 8;

    const bf16x8 a0 = *(const bf16x8*)(wl3 + 0 * 512);
    const bf16x8 a1 = *(const bf16x8*)(wl3 + 1 * 512);

    f32x4 acc[4][2];
#pragma unroll
    for (int f = 0; f < 4; ++f)
#pragma unroll
        for (int cf = 0; cf < 2; ++cf)
            acc[f][cf] = (f32x4){0.f, 0.f, 0.f, 0.f};

#pragma unroll
    for (int f = 0; f < 4; ++f) {
        const int c0 = f * 16;
        bf16x8 bv;
#pragma unroll
        for (int j = 0; j < 8; ++j) {
            const int k = kg * 8 + j;
            ushort val = 0;
            if (k < 27) {
                const int tap = k / 3, ci = k - 3 * tap;
                const int dh = tap / 3, dwp = tap - 3 * dh;
                val = ihalo[((r + dh) * HALO_W2 + (c0 + dwp + l15)) * 4 + ci];
            }
            bv[j] = (short)val;
        }
        acc[f][0] = __builtin_amdgcn_mfma_f32_16x16x32_bf16(a0, bv, acc[f][0], 0, 0, 0);
        acc[f][1] = __builtin_amdgcn_mfma_f32_16x16x32_bf16(a1, bv, acc[f][1], 0, 0, 0);
    }

#pragma unroll
    for (int f = 0; f < 4; ++f) {
        const int c0 = f * 16;
        const long gpx = (long)b * HWPX + (long)(h0 + r) * WID + (w0 + c0 + l15);
#pragma unroll
        for (int cf = 0; cf < 2; ++cf) {
            const int co0 = cf * 16 + kg * 4;
            const float4 bv4 = *(const float4*)(&s_bias[co0]);
            uint2 o;
            o.x = pack2bf(gelu_f(acc[f][cf][0] + bv4.x), gelu_f(acc[f][cf][1] + bv4.y));
            o.y = pack2bf(gelu_f(acc[f][cf][2] + bv4.z), gelu_f(acc[f][cf][3] + bv4.w));
            *(uint2*)(out + gpx * 32 + co0) = o;
        }
    }
}

// ---------------------------------------------------------------------------
// K6: MFMA 32->32 conv (r14 measured-best structure).
// ---------------------------------------------------------------------------
template <bool HAS_RES>
__global__ __launch_bounds__(512, 6) void conv32_mfma(
    const ushort* __restrict__ in, const ushort* __restrict__ res,
    const ushort* __restrict__ wpk, const float* __restrict__ bias,
    const float* __restrict__ bn_g, const float* __restrict__ bn_bt,
    ushort* __restrict__ out)
{
    __shared__ ushort halo[HALO_H2 * HALO_W2 * CSTR];   // 52800 B
    __shared__ float s_scale[32], s_shift[32];

    const int tid = threadIdx.x;
    const int bid = blockIdx.x;
    const int t   = (bid & 7) * CHUNK + (bid >> 3);
    const int tx  = t % NTX;
    const int rem = t / NTX;
    const int ty  = rem % NTY;
    const int b   = rem / NTY;
    const int h0 = ty * TH2;
    const int w0 = tx * TW2;

    if (tid < 32) {
        float sg = bn_g[tid] * 0.9999950000375f;   // g*(1+1e-5)^-0.5
        s_scale[tid] = sg;
        s_shift[tid] = bias[tid] * sg + bn_bt[tid];
    }

    const ushort* inb = in + (long)b * HWPX * 32;
    for (int i = tid; i < HALO_H2 * HALO_W2 * 4; i += 512) {
        const int row = i / (HALO_W2 * 4);
        const int rem2 = i - row * (HALO_W2 * 4);
        const int px = rem2 >> 2, q = rem2 & 3;
        const int gh = h0 + row - 1, gw = w0 + px - 1;
        uint4 v = make_uint4(0u, 0u, 0u, 0u);
        if (gh >= 0 && gh < HGT && gw >= 0 && gw < WID)
            v = *(const uint4*)(inb + ((long)gh * WID + gw) * 32 + q * 8);
        *(uint4*)(&halo[(row * HALO_W2 + px) * CSTR + q * 8]) = v;
    }
    __syncthreads();

    const int lane = tid & 63, wid = tid >> 6;
    const int l15 = lane & 15, kg = lane >> 4;
    const int r = wid;
    const ushort* wlane = wpk + lane * 8;

    f32x4 acc[4][2];
#pragma unroll
    for (int f = 0; f < 4; ++f)
#pragma unroll
        for (int cf = 0; cf < 2; ++cf)
            acc[f][cf] = (f32x4){0.f, 0.f, 0.f, 0.f};

#pragma unroll
    for (int tap = 0; tap < 9; ++tap) {
        const int dh = tap / 3, dw = tap - dh * 3;
        const bf16x8 a0 = *(const bf16x8*)(wlane + (tap * 2 + 0) * 512);
        const bf16x8 a1 = *(const bf16x8*)(wlane + (tap * 2 + 1) * 512);
#pragma unroll
        for (int f = 0; f < 4; ++f) {
            const int c0 = f * 16;
            const bf16x8 bfv = *(const bf16x8*)(
                &halo[((r + dh) * HALO_W2 + (c0 + dw + l15)) * CSTR + kg * 8]);
            acc[f][0] = __builtin_amdgcn_mfma_f32_16x16x32_bf16(a0, bfv, acc[f][0], 0, 0, 0);
            acc[f][1] = __builtin_amdgcn_mfma_f32_16x16x32_bf16(a1, bfv, acc[f][1], 0, 0, 0);
        }
    }

#pragma unroll
    for (int f = 0; f < 4; ++f) {
        const int c0 = f * 16;
        const long gpx = (long)b * HWPX + (long)(h0 + r) * WID + (w0 + c0 + l15);
#pragma unroll
        for (int cf = 0; cf < 2; ++cf) {
            const int co0 = cf * 16 + kg * 4;
            const float4 sc = *(const float4*)(&s_scale[co0]);
            const float4 sh = *(const float4*)(&s_shift[co0]);
            float v0 = acc[f][cf][0] * sc.x + sh.x;
            float v1 = acc[f][cf][1] * sc.y + sh.y;
            float v2 = acc[f][cf][2] * sc.z + sh.z;
            float v3 = acc[f][cf][3] * sc.w + sh.w;
            if (HAS_RES) {
                const uint2 rv = *(const uint2*)(res + gpx * 32 + co0);
                v0 += bf2f_lo(rv.x); v1 += bf2f_hi(rv.x);
                v2 += bf2f_lo(rv.y); v3 += bf2f_hi(rv.y);
            }
            uint2 o;
            o.x = pack2bf(gelu_f(v0), gelu_f(v1));
            o.y = pack2bf(gelu_f(v2), gelu_f(v3));
            *(uint2*)(out + gpx * 32 + co0) = o;
        }
    }
}

// ---------------------------------------------------------------------------
// K7: MFMA 32->3 conv. FINAL=false additionally computes the trilinear LUT
// apply for its 512 tile pixels (1 px/thread) -> comb slots 0..3; conv
// result -> comb slots 4..7. FINAL=true: conv + img -> fp32 NCHW d_out.
// ---------------------------------------------------------------------------
template <bool FINAL>
__global__ __launch_bounds__(512, 4) void conv_out3_mfma(
    const ushort* __restrict__ in, const ushort* __restrict__ wpk,
    const float* __restrict__ bias, const float* __restrict__ img,
    float* __restrict__ outp, ushort* __restrict__ comb,
    const float* __restrict__ clut, const float* __restrict__ recon)
{
    __shared__ ushort halo[HALO_H2 * HALO_W2 * CSTR];   // 52800 B

    const int tid = threadIdx.x;
    const int bid = blockIdx.x;
    const int t   = (bid & 7) * CHUNK + (bid >> 3);
    const int tx  = t % NTX;
    const int rem = t / NTX;
    const int ty  = rem % NTY;
    const int b   = rem / NTY;
    const int h0 = ty * TH2;
    const int w0 = tx * TW2;

    const ushort* inb = in + (long)b * HWPX * 32;
    for (int i = tid; i < HALO_H2 * HALO_W2 * 4; i += 512) {
        const int row = i / (HALO_W2 * 4);
        const int rem2 = i - row * (HALO_W2 * 4);
        const int px = rem2 >> 2, q = rem2 & 3;
        const int gh = h0 + row - 1, gw = w0 + px - 1;
        uint4 v = make_uint4(0u, 0u, 0u, 0u);
        if (gh >= 0 && gh < HGT && gw >= 0 && gw < WID)
            v = *(const uint4*)(inb + ((long)gh * WID + gw) * 32 + q * 8);
        *(uint4*)(&halo[(row * HALO_W2 + px) * CSTR + q * 8]) = v;
    }
    __syncthreads();

    const int lane = tid & 63, wid = tid >> 6;
    const int l15 = lane & 15, kg = lane >> 4;
    const int r = wid;
    const ushort* wlane = wpk + lane * 8;

    f32x4 acc[4];
#pragma unroll
    for (int f = 0; f < 4; ++f) acc[f] = (f32x4){0.f, 0.f, 0.f, 0.f};

#pragma unroll
    for (int tap = 0; tap < 9; ++tap) {
        const int dh = tap / 3, dw = tap - dh * 3;
        const bf16x8 a0 = *(const bf16x8*)(wlane + (tap * 2 + 0) * 512);
#pragma unroll
        for (int f = 0; f < 4; ++f) {
            const int c0 = f * 16;
            const bf16x8 bfv = *(const bf16x8*)(
                &halo[((r + dh) * HALO_W2 + (c0 + dw + l15)) * CSTR + kg * 8]);
            acc[f] = __builtin_amdgcn_mfma_f32_16x16x32_bf16(a0, bfv, acc[f], 0, 0, 0);
        }
    }

    if (kg == 0) {   // rows 0..2 of D valid
        const float b0 = bias[0], b1 = bias[1], b2v = bias[2];
#pragma unroll
        for (int f = 0; f < 4; ++f) {
            const int p = (h0 + r) * WID + (w0 + f * 16 + l15);
            const long gpx = (long)b * HWPX + p;
            float v0 = acc[f][0] + b0;
            float v1 = acc[f][1] + b1;
            float v2 = acc[f][2] + b2v;
            if (FINAL) {
                outp[(long)(b * 3 + 0) * HWPX + p] = v0 + img[(long)(b * 3 + 0) * HWPX + p];
                outp[(long)(b * 3 + 1) * HWPX + p] = v1 + img[(long)(b * 3 + 1) * HWPX + p];
                outp[(long)(b * 3 + 2) * HWPX + p] = v2 + img[(long)(b * 3 + 2) * HWPX + p];
            } else {
                uint2 u;
                u.x = pack2bf(v0, v1);
                u.y = pack2bf(v2, 0.f);
                *(uint2*)(comb + gpx * 8 + 4) = u;
            }
        }
    }

    if (!FINAL) {
        // fused trilinear LUT apply: 1 px/thread over the 8x64 tile
        const int row = tid >> 6, col = tid & 63;
        const int p = (h0 + row) * WID + (w0 + col);
        const float* rc = recon + (long)b * 3 * HWPX;
        float cr = fminf(fmaxf(rc[p] * 32.f, 0.f), 32.f);
        float cg = fminf(fmaxf(rc[HWPX + p] * 32.f, 0.f), 32.f);
        float cb = fminf(fmaxf(rc[2 * HWPX + p] * 32.f, 0.f), 32.f);
        float fr = fminf(floorf(cr), 31.f);
        float fg = fminf(floorf(cg), 31.f);
        float fb = fminf(floorf(cb), 31.f);
        float tr = cr - fr, tg = cg - fg, tb_ = cb - fb;
        int idx = (((int)fr * GSZ + (int)fg) * GSZ + (int)fb);
        float c[3];
#pragma unroll
        for (int ch = 0; ch < 3; ++ch) {
            const float* lut = clut + (long)(b * 3 + ch) * G3;
            float v000 = lut[idx],                  v001 = lut[idx + 1];
            float v010 = lut[idx + GSZ],            v011 = lut[idx + GSZ + 1];
            float v100 = lut[idx + GSZ * GSZ],      v101 = lut[idx + GSZ * GSZ + 1];
            float v110 = lut[idx + GSZ * GSZ + GSZ], v111 = lut[idx + GSZ * GSZ + GSZ + 1];
            float c00 = v000 + (v001 - v000) * tb_;
            float c01 = v010 + (v011 - v010) * tb_;
            float c10 = v100 + (v101 - v100) * tb_;
            float c11 = v110 + (v111 - v110) * tb_;
            float c0 = c00 + (c01 - c00) * tg;
            float c1 = c10 + (c11 - c10) * tg;
            c[ch] = c0 + (c1 - c0) * tr;
        }
        uint2 u;
        u.x = pack2bf(c[0], c[1]);
        u.y = pack2bf(c[2], 0.f);
        *(uint2*)(comb + ((long)b * HWPX + p) * 8) = u;
    }
}

// ---------------------------------------------------------------------------
// K8: MFMA 6->32 conv (comb bf16 [px][8] -> act NHWC bf16), gelu.
// K=54 padded to 64, k=(tap*6+ci). Comb halo in LDS (10.5 KB). 16 MFMA/wave.
// ---------------------------------------------------------------------------
__global__ __launch_bounds__(512) void conv_in6_mfma(
    const ushort* __restrict__ comb, const ushort* __restrict__ wpk6,
    const float* __restrict__ bias, ushort* __restrict__ out)
{
    __shared__ ushort chalo[HALO_H2 * HALO_W2 * 8];   // 10560 B
    __shared__ float s_bias[32];

    const int tid = threadIdx.x;
    const int bid = blockIdx.x;
    const int t   = (bid & 7) * CHUNK + (bid >> 3);
    const int tx  = t % NTX;
    const int rem = t / NTX;
    const int ty  = rem % NTY;
    const int b   = rem / NTY;
    const int h0 = ty * TH2;
    const int w0 = tx * TW2;

    if (tid < 32) s_bias[tid] = bias[tid];

    const ushort* cb = comb + (long)b * HWPX * 8;
    for (int i = tid; i < HALO_H2 * HALO_W2; i += 512) {
        const int row = i / HALO_W2, px = i - row * HALO_W2;
        const int gh = h0 + row - 1, gw = w0 + px - 1;
        uint4 v = make_uint4(0u, 0u, 0u, 0u);
        if (gh >= 0 && gh < HGT && gw >= 0 && gw < WID)
            v = *(const uint4*)(cb + ((long)gh * WID + gw) * 8);
        *(uint4*)(&chalo[i * 8]) = v;
    }
    __syncthreads();

    const int lane = tid & 63, wid = tid >> 6;
    const int l15 = lane & 15, kg = lane >> 4;
    const int r = wid;
    const ushort* wl6 = wpk6 + lane * 8;

    f32x4 acc[4][2];
#pragma unroll
    for (int f = 0; f < 4; ++f)
#pragma unroll
        for (int cf = 0; cf < 2; ++cf)
            acc[f][cf] = (f32x4){0.f, 0.f, 0.f, 0.f};

#pragma unroll
    for (int ks = 0; ks < 2; ++ks) {
        const bf16x8 a0 = *(const bf16x8*)(wl6 + (ks * 2 + 0) * 512);
        const bf16x8 a1 = *(const bf16x8*)(wl6 + (ks * 2 + 1) * 512);
#pragma unroll
        for (int f = 0; f < 4; ++f) {
            const int c0 = f * 16;
            bf16x8 bv;
#pragma unroll
            for (int j = 0; j < 8; ++j) {
                const int k = ks * 32 + kg * 8 + j;
                ushort val = 0;
                if (k < 54) {
                    const int tap = k / 6, ci = k - 6 * tap;
                    const int dh = tap / 3, dwp = tap - 3 * dh;
                    const int slot = ci + (ci >= 3 ? 1 : 0);
                    val = chalo[((r + dh) * HALO_W2 + (c0 + dwp + l15)) * 8 + slot];
                }
                bv[j] = (short)val;
            }
            acc[f][0] = __builtin_amdgcn_mfma_f32_16x16x32_bf16(a0, bv, acc[f][0], 0, 0, 0);
            acc[f][1] = __builtin_amdgcn_mfma_f32_16x16x32_bf16(a1, bv, acc[f][1], 0, 0, 0);
        }
    }

#pragma unroll
    for (int f = 0; f < 4; ++f) {
        const int c0 = f * 16;
        const long gpx = (long)b * HWPX + (long)(h0 + r) * WID + (w0 + c0 + l15);
#pragma unroll
        for (int cf = 0; cf < 2; ++cf) {
            const int co0 = cf * 16 + kg * 4;
            const float4 bv4 = *(const float4*)(&s_bias[co0]);
            uint2 o;
            o.x = pack2bf(gelu_f(acc[f][cf][0] + bv4.x), gelu_f(acc[f][cf][1] + bv4.y));
            o.y = pack2bf(gelu_f(acc[f][cf][2] + bv4.z), gelu_f(acc[f][cf][3] + bv4.w));
            *(uint2*)(out + gpx * 32 + co0) = o;
        }
    }
}

// ---------------------------------------------------------------------------
extern "C" void kernel_launch(void* const* d_in, const int* in_sizes, int n_in,
                              void* d_out, int out_size, void* d_ws, size_t ws_size,
                              hipStream_t stream)
{
    const int*   tokens  = (const int*)d_in[0];
    const float* img     = (const float*)d_in[1];
    const float* recon   = (const float*)d_in[2];
    const float* emb     = (const float*)d_in[3];
    const float* agg_w1  = (const float*)d_in[4];
    const float* agg_b1  = (const float*)d_in[5];
    const float* agg_w2  = (const float*)d_in[6];
    const float* agg_b2  = (const float*)d_in[7];
    const float* lut_w1  = (const float*)d_in[8];
    const float* lut_b1  = (const float*)d_in[9];
    const float* lut_w2  = (const float*)d_in[10];
    const float* lut_b2  = (const float*)d_in[11];
    const float* wg_w1   = (const float*)d_in[12];
    const float* wg_b1   = (const float*)d_in[13];
    const float* wg_w2   = (const float*)d_in[14];
    const float* wg_b2   = (const float*)d_in[15];
    const float* rp_cin_w = (const float*)d_in[16];
    const float* rp_cin_b = (const float*)d_in[17];
    const float* rp_rbA_w = (const float*)d_in[18];
    const float* rp_rbA_b = (const float*)d_in[19];
    const float* rp_rbA_g = (const float*)d_in[20];
    const float* rp_rbA_bt= (const float*)d_in[21];
    const float* rp_rbB_w = (const float*)d_in[22];
    const float* rp_rbB_b = (const float*)d_in[23];
    const float* rp_rbB_g = (const float*)d_in[24];
    const float* rp_rbB_bt= (const float*)d_in[25];
    const float* rp_cout_w= (const float*)d_in[26];
    const float* rp_cout_b= (const float*)d_in[27];
    const float* fu_cin_w = (const float*)d_in[28];
    const float* fu_cin_b = (const float*)d_in[29];
    const float* fu_rbA_w = (const float*)d_in[30];
    const float* fu_rbA_b = (const float*)d_in[31];
    const float* fu_rbA_g = (const float*)d_in[32];
    const float* fu_rbA_bt= (const float*)d_in[33];
    const float* fu_rbB_w = (const float*)d_in[34];
    const float* fu_rbB_b = (const float*)d_in[35];
    const float* fu_rbB_g = (const float*)d_in[36];
    const float* fu_rbB_bt= (const float*)d_in[37];
    const float* fu_cout_w= (const float*)d_in[38];
    const float* fu_cout_b= (const float*)d_in[39];

    float* ws = (float*)d_ws;
    float*  h3      = ws;                       // 1024
    float*  lwv     = ws + 1024;                // 32
    float*  partial = ws + 2048;                // 65536
    float*  clut    = ws + 69632;               // 431244
    ushort* wpack   = (ushort*)(ws + 524288);   // 58368 ushorts
    ushort* comb    = (ushort*)(ws + 589824);   // 4*HWPX*8 ushorts (bf16)
    ushort* act0    = (ushort*)(ws + 3145728);  // 18874368 ushorts
    ushort* act1    = (ushort*)(ws + 12582912);
    ushort* act2    = (ushort*)(ws + 22020096);
    float*  outp    = (float*)d_out;

    // pack all MFMA A-fragment tables
    pack_wconv_kernel<<<dim3(8), dim3(256), 0, stream>>>(
        rp_rbA_w, rp_rbB_w, fu_rbA_w, fu_rbB_w, rp_cout_w, fu_cout_w,
        fu_cin_w, rp_cin_w, wpack);

    // token head
    emb_partial_kernel<<<dim3(64, BB), dim3(256), 0, stream>>>(tokens, emb, partial);
    mlp_head_kernel<<<dim3(BB), dim3(1024), 0, stream>>>(
        partial, agg_w1, agg_b1, agg_w2, agg_b2,
        lut_w1, lut_b1, wg_w1, wg_b1, wg_w2, wg_b2, h3, lwv);

    // fused LUT GEMM + combine -> clut
    lut_fused_kernel<<<dim3((3 * G3 + 255) / 256), dim3(256), 0, stream>>>(
        h3, lwv, lut_w2, lut_b2, clut);

    const dim3 gm(NBLK), bm(512);

    // proc branch: img -> act0 -> act1 -> act2
    conv_in3_mfma<<<gm, bm, 0, stream>>>(img, wpack + WPK_IN3, rp_cin_b, act0);
    conv32_mfma<false><<<gm, bm, 0, stream>>>(
        act0, nullptr, wpack + 0 * 9216, rp_rbA_b, rp_rbA_g, rp_rbA_bt, act1);
    conv32_mfma<true><<<gm, bm, 0, stream>>>(
        act1, act0, wpack + 1 * 9216, rp_rbB_b, rp_rbB_g, rp_rbB_bt, act2);

    // proc 32->3 (MFMA) + fused LUT apply -> comb
    conv_out3_mfma<false><<<gm, bm, 0, stream>>>(
        act2, wpack + 4 * 9216, rp_cout_b, nullptr, nullptr, comb, clut, recon);

    // fuse branch: comb -> act0 -> act1 -> act2 -> d_out (+img)
    conv_in6_mfma<<<gm, bm, 0, stream>>>(comb, wpack + WPK_IN6, fu_cin_b, act0);
    conv32_mfma<false><<<gm, bm, 0, stream>>>(
        act0, nullptr, wpack + 2 * 9216, fu_rbA_b, fu_rbA_g, fu_rbA_bt, act1);
    conv32_mfma<true><<<gm, bm, 0, stream>>>(
        act1, act0, wpack + 3 * 9216, fu_rbB_b, fu_rbB_g, fu_rbB_bt, act2);
    conv_out3_mfma<true><<<gm, bm, 0, stream>>>(
        act2, wpack + 5 * 9216, fu_cout_b, img, outp, nullptr, nullptr, nullptr);
}

// Round 19
// 466.357 us; speedup vs baseline: 2.1241x; 1.0215x over previous
//
#include <hip/hip_runtime.h>
#include <hip/hip_bf16.h>
#include <math.h>

// Problem constants
#define BB    4
#define TT    1024
#define EE    256
#define HIDD  256
#define LLUT  8
#define HGT   384
#define WID   384
#define HWPX  147456      // 384*384
#define GSZ   33
#define G3    35937       // 33^3
#define NCOL  862488      // L*3*G3

typedef __attribute__((ext_vector_type(8))) short bf16x8;   // 8 bf16 = 4 VGPRs
typedef __attribute__((ext_vector_type(4))) float f32x4;

// fast gelu (tanh form): max abs dev from exact erf-gelu ~1e-3, threshold 2e-2
__device__ __forceinline__ float gelu_f(float x) {
    float s = 1.5957691216057308f * x * (1.0f + 0.044715f * x * x);
    float e = __expf(s);
    return x - x / (e + 1.0f);   // x*sigmoid(s); safe at +-inf
}

__device__ __forceinline__ ushort f2bf(float x) {
    uint u = __float_as_uint(x);
    return (ushort)((u + 0x7FFFu + ((u >> 16) & 1u)) >> 16);   // RNE
}
__device__ __forceinline__ uint pack2bf(float a, float b) {
    return (uint)f2bf(a) | ((uint)f2bf(b) << 16);
}
__device__ __forceinline__ float bf2f_lo(uint u) { return __uint_as_float(u << 16); }
__device__ __forceinline__ float bf2f_hi(uint u) { return __uint_as_float(u & 0xFFFF0000u); }

// conv tiling (shared by MFMA conv kernels)
#define TH2 8
#define TW2 64
#define NTX (WID / TW2)          // 6
#define NTY (HGT / TH2)          // 48
#define NBLK (NTX * NTY * BB)    // 1152
#define CHUNK (NBLK / 8)         // 144
#define HALO_H2 10
#define HALO_H3 11               // in3/in6: taps up to dh=3 (zero-weighted)
#define HALO_W2 66
#define CSTR 40   // padded ushort stride per pixel (80 B)

// wpack layout (ushorts):
//   0..4*9216      : 32->32 convs (rpA, rpB, fuA, fuB)
//   4*9216..6*9216 : 32->3 convs (rp_cout, fu_cout), rows>=3 zero
//   55296..58368   : 6->32 conv (fu_cin), k=tap*8+slot, K=96 (3 mfma)
//   58368..61440   : 3->32 conv (rp_cin), same k-map, slots 3..7 zero
#define WPK_IN6 55296
#define WPK_IN3 58368

// ---------------------------------------------------------------------------
// K-1: pack MFMA A-fragment tables (lane-linear bf16).
// ---------------------------------------------------------------------------
__global__ __launch_bounds__(256) void pack_wconv_kernel(
    const float* __restrict__ w0, const float* __restrict__ w1,
    const float* __restrict__ w2, const float* __restrict__ w3,
    const float* __restrict__ c0w, const float* __restrict__ c1w,
    const float* __restrict__ w6, const float* __restrict__ w7,
    ushort* __restrict__ wpk)
{
    const int layer = blockIdx.x;
    if (layer < 6) {
        const float* w = (layer == 0) ? w0 : (layer == 1) ? w1 :
                         (layer == 2) ? w2 : (layer == 3) ? w3 :
                         (layer == 4) ? c0w : c1w;
        const bool small = (layer >= 4);
        ushort* dst = wpk + layer * 9216;
        for (int i = threadIdx.x; i < 9216; i += 256) {
            const int j    = i & 7;
            const int lane = (i >> 3) & 63;
            const int half = (i >> 9) & 1;
            const int tap  = i >> 10;
            const int co = half * 16 + (lane & 15);
            const int ci = (lane >> 4) * 8 + j;
            float v = 0.f;
            if (!small || co < 3) v = w[co * 288 + ci * 9 + tap];
            dst[i] = f2bf(v);
        }
    } else {
        // layers 6 (in6) / 7 (in3): k = tap*8 + slot, K=96 (3 mfma x 2 halves)
        // chunk c6 = m*2+half; entry index = c6*512 + lane*8 + j
        const bool is6 = (layer == 6);
        ushort* dst = wpk + (is6 ? WPK_IN6 : WPK_IN3);
        for (int i = threadIdx.x; i < 3072; i += 256) {
            const int j    = i & 7;
            const int lane = (i >> 3) & 63;
            const int c6   = i >> 9;          // 0..5
            const int m = c6 >> 1, half = c6 & 1;
            const int co = half * 16 + (lane & 15);
            const int k  = m * 32 + (lane >> 4) * 8 + j;
            const int tap = k >> 3, slot = k & 7;
            float v = 0.f;
            if (tap < 9) {
                if (is6) {
                    // comb slots: 0..2 fused(ci 0..2), 4..6 proc(ci 3..5)
                    int ci = (slot < 3) ? slot : ((slot >= 4 && slot < 7) ? slot - 1 : -1);
                    if (ci >= 0) v = w6[co * 54 + ci * 9 + tap];
                } else {
                    if (slot < 3) v = w7[co * 27 + slot * 9 + tap];
                }
            }
            dst[i] = f2bf(v);
        }
    }
}

// ---------------------------------------------------------------------------
// K0: embedding-mean partial sums. grid (64, B).
// ---------------------------------------------------------------------------
__global__ __launch_bounds__(256) void emb_partial_kernel(
    const int* __restrict__ tokens, const float* __restrict__ emb,
    float* __restrict__ partial)
{
    const int s = blockIdx.x, b = blockIdx.y, tid = threadIdx.x;
    const int* tok = tokens + b * TT + s * 16;
    float acc = 0.f;
#pragma unroll
    for (int t = 0; t < 16; ++t) acc += emb[tok[t] * EE + tid];
    partial[(b * 64 + s) * EE + tid] = acc;
}

// ---------------------------------------------------------------------------
// K1: fused token head, latency-parallel.
// ---------------------------------------------------------------------------
__global__ __launch_bounds__(1024) void mlp_head_kernel(
    const float* __restrict__ partial,
    const float* __restrict__ aw1, const float* __restrict__ ab1,
    const float* __restrict__ aw2, const float* __restrict__ ab2,
    const float* __restrict__ lw1, const float* __restrict__ lb1,
    const float* __restrict__ gw1, const float* __restrict__ gb1,
    const float* __restrict__ gw2, const float* __restrict__ gb2,
    float* __restrict__ h3_out, float* __restrict__ lw_out)
{
    const int b = blockIdx.x;
    const int tid = threadIdx.x;
    const int o = tid & 255;
    const int q = tid >> 8;
    __shared__ float tf[256], h1[256], tf2s[256], h4[64], lg[8];
    __shared__ float red[4][256];

    {
        float acc = 0.f;
#pragma unroll
        for (int s = 0; s < 16; ++s)
            acc += partial[(b * 64 + q * 16 + s) * EE + o];
        red[q][o] = acc;
    }
    __syncthreads();
    if (tid < 256)
        tf[tid] = (red[0][tid] + red[1][tid] + red[2][tid] + red[3][tid]) * (1.0f / TT);
    __syncthreads();

    {
        float s = 0.f;
#pragma unroll 8
        for (int j = 0; j < 64; ++j) {
            const int k = (q << 6) + j;
            s += tf[k] * aw1[k * HIDD + o];
        }
        red[q][o] = s;
    }
    __syncthreads();
    if (tid < 256)
        h1[tid] = gelu_f(red[0][tid] + red[1][tid] + red[2][tid] + red[3][tid] + ab1[tid]);
    __syncthreads();

    {
        float s = 0.f;
#pragma unroll 8
        for (int j = 0; j < 64; ++j) {
            const int k = (q << 6) + j;
            s += h1[k] * aw2[k * HIDD + o];
        }
        red[q][o] = s;
    }
    __syncthreads();
    if (tid < 256)
        tf2s[tid] = red[0][tid] + red[1][tid] + red[2][tid] + red[3][tid] + ab2[tid];
    __syncthreads();

    {
        float s = 0.f;
#pragma unroll 8
        for (int j = 0; j < 64; ++j) {
            const int k = (q << 6) + j;
            s += tf2s[k] * lw1[k * HIDD + o];
        }
        red[q][o] = s;
    }
    __syncthreads();
    if (tid < 256)
        h3_out[b * HIDD + tid] =
            gelu_f(red[0][tid] + red[1][tid] + red[2][tid] + red[3][tid] + lb1[tid]);
    __syncthreads();

    {
        const int o64 = tid & 63, q16 = tid >> 6;
        float s = 0.f;
#pragma unroll
        for (int j = 0; j < 16; ++j) {
            const int k = q16 * 16 + j;
            s += tf2s[k] * gw1[k * 64 + o64];
        }
        ((float*)red)[q16 * 64 + o64] = s;
    }
    __syncthreads();
    if (tid < 64) {
        float s = gb1[tid];
#pragma unroll
        for (int r = 0; r < 16; ++r) s += ((float*)red)[r * 64 + tid];
        h4[tid] = gelu_f(s);
    }
    __syncthreads();

    if (tid < 8) {
        float s = gb2[tid];
#pragma unroll 8
        for (int k = 0; k < 64; ++k) s += h4[k] * gw2[k * LLUT + tid];
        lg[tid] = s;
    }
    __syncthreads();
    if (tid == 0) {
        float m = lg[0];
        for (int i = 1; i < LLUT; ++i) m = fmaxf(m, lg[i]);
        float ssum = 0.f, ex[LLUT];
        for (int i = 0; i < LLUT; ++i) { ex[i] = expf(lg[i] - m); ssum += ex[i]; }
        for (int i = 0; i < LLUT; ++i) lw_out[b * LLUT + i] = ex[i] / ssum;
    }
}

// ---------------------------------------------------------------------------
// K2: fused LUT-GEMM + softmax-combine -> clut (883 MB w2 stream).
// ---------------------------------------------------------------------------
__global__ __launch_bounds__(256) void lut_fused_kernel(
    const float* __restrict__ h3, const float* __restrict__ lwv,
    const float* __restrict__ w2, const float* __restrict__ b2,
    float* __restrict__ clut)
{
    __shared__ float h[BB * HIDD];
    __shared__ float lws[BB * LLUT];
    const int tid = threadIdx.x;
    for (int i = tid; i < BB * HIDD; i += 256) h[i] = h3[i];
    if (tid < BB * LLUT) lws[tid] = lwv[tid];
    __syncthreads();

    const int idx = blockIdx.x * 256 + tid;
    if (idx >= 3 * G3) return;
    const int c = idx / G3, v = idx - c * G3;

    float acc[BB][LLUT];
#pragma unroll
    for (int b = 0; b < BB; ++b)
#pragma unroll
        for (int l = 0; l < LLUT; ++l) acc[b][l] = 0.f;

    const float* wbase = w2 + (long)c * G3 + v;   // + l*3*G3 + k*NCOL
#pragma unroll 4
    for (int k = 0; k < HIDD; ++k) {
        const float* row = wbase + (long)k * NCOL;
        float wl[LLUT];
#pragma unroll
        for (int l = 0; l < LLUT; ++l) wl[l] = row[l * 3 * G3];
#pragma unroll
        for (int b = 0; b < BB; ++b) {
            const float hb = h[b * HIDD + k];
#pragma unroll
            for (int l = 0; l < LLUT; ++l) acc[b][l] += wl[l] * hb;
        }
    }

    float bb[LLUT];
#pragma unroll
    for (int l = 0; l < LLUT; ++l) bb[l] = b2[(long)(l * 3 + c) * G3 + v];

#pragma unroll
    for (int b = 0; b < BB; ++b) {
        float s = 0.f;
#pragma unroll
        for (int l = 0; l < LLUT; ++l) s += lws[b * LLUT + l] * (acc[b][l] + bb[l]);
        clut[(long)(b * 3 + c) * G3 + v] = s;
    }
}

// ---------------------------------------------------------------------------
// K5 v2: MFMA 3->32 conv. img staged as bf16 [11][66][8] (slots 0..2 = ch,
// 3..7 = 0). k = tap*8+slot, 3 mfma x 2 halves; each B-frag = one b128.
// ---------------------------------------------------------------------------
__global__ __launch_bounds__(512) void conv_in3_mfma(
    const float* __restrict__ img, const ushort* __restrict__ wpk3,
    const float* __restrict__ bias, ushort* __restrict__ out)
{
    __shared__ ushort ihalo[HALO_H3 * HALO_W2 * 8];   // 11616 B
    __shared__ float s_bias[32];

    const int tid = threadIdx.x;
    const int bid = blockIdx.x;
    const int t   = (bid & 7) * CHUNK + (bid >> 3);
    const int tx  = t % NTX;
    const int rem = t / NTX;
    const int ty  = rem % NTY;
    const int b   = rem / NTY;
    const int h0 = ty * TH2;
    const int w0 = tx * TW2;

    if (tid < 32) s_bias[tid] = bias[tid];

    const float* imb = img + (long)b * 3 * HWPX;
    for (int i = tid; i < HALO_H3 * HALO_W2; i += 512) {
        const int row = i / HALO_W2, px = i - row * HALO_W2;
        const int gh = h0 + row - 1, gw = w0 + px - 1;
        float c0v = 0.f, c1v = 0.f, c2v = 0.f;
        if (gh >= 0 && gh < HGT && gw >= 0 && gw < WID) {
            const int p = gh * WID + gw;
            c0v = imb[p]; c1v = imb[HWPX + p]; c2v = imb[2 * HWPX + p];
        }
        uint4 u; u.x = pack2bf(c0v, c1v); u.y = pack2bf(c2v, 0.f);
        u.z = 0u; u.w = 0u;
        *(uint4*)(&ihalo[i * 8]) = u;
    }
    __syncthreads();

    const int lane = tid & 63, wid = tid >> 6;
    const int l15 = lane & 15, kg = lane >> 4;
    const int r = wid;
    const ushort* wl3 = wpk3 + lane * 8;

    f32x4 acc[4][2];
#pragma unroll
    for (int f = 0; f < 4; ++f)
#pragma unroll
        for (int cf = 0; cf < 2; ++cf)
            acc[f][cf] = (f32x4){0.f, 0.f, 0.f, 0.f};

#pragma unroll
    for (int m = 0; m < 3; ++m) {
        const int tap = m * 4 + kg;            // 0..11 (taps>=9 zero-weighted)
        const int dh = tap / 3, dwp = tap - 3 * (tap / 3);
        const bf16x8 a0 = *(const bf16x8*)(wl3 + (m * 2 + 0) * 512);
        const bf16x8 a1 = *(const bf16x8*)(wl3 + (m * 2 + 1) * 512);
#pragma unroll
        for (int f = 0; f < 4; ++f) {
            const int c0 = f * 16;
            const bf16x8 bv = *(const bf16x8*)(
                &ihalo[((r + dh) * HALO_W2 + (c0 + dwp + l15)) * 8]);
            acc[f][0] = __builtin_amdgcn_mfma_f32_16x16x32_bf16(a0, bv, acc[f][0], 0, 0, 0);
            acc[f][1] = __builtin_amdgcn_mfma_f32_16x16x32_bf16(a1, bv, acc[f][1], 0, 0, 0);
        }
    }

#pragma unroll
    for (int f = 0; f < 4; ++f) {
        const int c0 = f * 16;
        const long gpx = (long)b * HWPX + (long)(h0 + r) * WID + (w0 + c0 + l15);
#pragma unroll
        for (int cf = 0; cf < 2; ++cf) {
            const int co0 = cf * 16 + kg * 4;
            const float4 bv4 = *(const float4*)(&s_bias[co0]);
            uint2 o;
            o.x = pack2bf(gelu_f(acc[f][cf][0] + bv4.x), gelu_f(acc[f][cf][1] + bv4.y));
            o.y = pack2bf(gelu_f(acc[f][cf][2] + bv4.z), gelu_f(acc[f][cf][3] + bv4.w));
            *(uint2*)(out + gpx * 32 + co0) = o;
        }
    }
}

// ---------------------------------------------------------------------------
// K6: MFMA 32->32 conv (r14 measured-best structure).
// ---------------------------------------------------------------------------
template <bool HAS_RES>
__global__ __launch_bounds__(512, 6) void conv32_mfma(
    const ushort* __restrict__ in, const ushort* __restrict__ res,
    const ushort* __restrict__ wpk, const float* __restrict__ bias,
    const float* __restrict__ bn_g, const float* __restrict__ bn_bt,
    ushort* __restrict__ out)
{
    __shared__ ushort halo[HALO_H2 * HALO_W2 * CSTR];   // 52800 B
    __shared__ float s_scale[32], s_shift[32];

    const int tid = threadIdx.x;
    const int bid = blockIdx.x;
    const int t   = (bid & 7) * CHUNK + (bid >> 3);
    const int tx  = t % NTX;
    const int rem = t / NTX;
    const int ty  = rem % NTY;
    const int b   = rem / NTY;
    const int h0 = ty * TH2;
    const int w0 = tx * TW2;

    if (tid < 32) {
        float sg = bn_g[tid] * 0.9999950000375f;   // g*(1+1e-5)^-0.5
        s_scale[tid] = sg;
        s_shift[tid] = bias[tid] * sg + bn_bt[tid];
    }

    const ushort* inb = in + (long)b * HWPX * 32;
    for (int i = tid; i < HALO_H2 * HALO_W2 * 4; i += 512) {
        const int row = i / (HALO_W2 * 4);
        const int rem2 = i - row * (HALO_W2 * 4);
        const int px = rem2 >> 2, q = rem2 & 3;
        const int gh = h0 + row - 1, gw = w0 + px - 1;
        uint4 v = make_uint4(0u, 0u, 0u, 0u);
        if (gh >= 0 && gh < HGT && gw >= 0 && gw < WID)
            v = *(const uint4*)(inb + ((long)gh * WID + gw) * 32 + q * 8);
        *(uint4*)(&halo[(row * HALO_W2 + px) * CSTR + q * 8]) = v;
    }
    __syncthreads();

    const int lane = tid & 63, wid = tid >> 6;
    const int l15 = lane & 15, kg = lane >> 4;
    const int r = wid;
    const ushort* wlane = wpk + lane * 8;

    f32x4 acc[4][2];
#pragma unroll
    for (int f = 0; f < 4; ++f)
#pragma unroll
        for (int cf = 0; cf < 2; ++cf)
            acc[f][cf] = (f32x4){0.f, 0.f, 0.f, 0.f};

#pragma unroll
    for (int tap = 0; tap < 9; ++tap) {
        const int dh = tap / 3, dw = tap - dh * 3;
        const bf16x8 a0 = *(const bf16x8*)(wlane + (tap * 2 + 0) * 512);
        const bf16x8 a1 = *(const bf16x8*)(wlane + (tap * 2 + 1) * 512);
#pragma unroll
        for (int f = 0; f < 4; ++f) {
            const int c0 = f * 16;
            const bf16x8 bfv = *(const bf16x8*)(
                &halo[((r + dh) * HALO_W2 + (c0 + dw + l15)) * CSTR + kg * 8]);
            acc[f][0] = __builtin_amdgcn_mfma_f32_16x16x32_bf16(a0, bfv, acc[f][0], 0, 0, 0);
            acc[f][1] = __builtin_amdgcn_mfma_f32_16x16x32_bf16(a1, bfv, acc[f][1], 0, 0, 0);
        }
    }

#pragma unroll
    for (int f = 0; f < 4; ++f) {
        const int c0 = f * 16;
        const long gpx = (long)b * HWPX + (long)(h0 + r) * WID + (w0 + c0 + l15);
#pragma unroll
        for (int cf = 0; cf < 2; ++cf) {
            const int co0 = cf * 16 + kg * 4;
            const float4 sc = *(const float4*)(&s_scale[co0]);
            const float4 sh = *(const float4*)(&s_shift[co0]);
            float v0 = acc[f][cf][0] * sc.x + sh.x;
            float v1 = acc[f][cf][1] * sc.y + sh.y;
            float v2 = acc[f][cf][2] * sc.z + sh.z;
            float v3 = acc[f][cf][3] * sc.w + sh.w;
            if (HAS_RES) {
                const uint2 rv = *(const uint2*)(res + gpx * 32 + co0);
                v0 += bf2f_lo(rv.x); v1 += bf2f_hi(rv.x);
                v2 += bf2f_lo(rv.y); v3 += bf2f_hi(rv.y);
            }
            uint2 o;
            o.x = pack2bf(gelu_f(v0), gelu_f(v1));
            o.y = pack2bf(gelu_f(v2), gelu_f(v3));
            *(uint2*)(out + gpx * 32 + co0) = o;
        }
    }
}

// ---------------------------------------------------------------------------
// K7: MFMA 32->3 conv. FINAL=false additionally computes the trilinear LUT
// apply for its 512 tile pixels (1 px/thread) -> comb slots 0..3; conv
// result -> comb slots 4..7. FINAL=true: conv + img -> fp32 NCHW d_out.
// ---------------------------------------------------------------------------
template <bool FINAL>
__global__ __launch_bounds__(512, 4) void conv_out3_mfma(
    const ushort* __restrict__ in, const ushort* __restrict__ wpk,
    const float* __restrict__ bias, const float* __restrict__ img,
    float* __restrict__ outp, ushort* __restrict__ comb,
    const float* __restrict__ clut, const float* __restrict__ recon)
{
    __shared__ ushort halo[HALO_H2 * HALO_W2 * CSTR];   // 52800 B

    const int tid = threadIdx.x;
    const int bid = blockIdx.x;
    const int t   = (bid & 7) * CHUNK + (bid >> 3);
    const int tx  = t % NTX;
    const int rem = t / NTX;
    const int ty  = rem % NTY;
    const int b   = rem / NTY;
    const int h0 = ty * TH2;
    const int w0 = tx * TW2;

    const ushort* inb = in + (long)b * HWPX * 32;
    for (int i = tid; i < HALO_H2 * HALO_W2 * 4; i += 512) {
        const int row = i / (HALO_W2 * 4);
        const int rem2 = i - row * (HALO_W2 * 4);
        const int px = rem2 >> 2, q = rem2 & 3;
        const int gh = h0 + row - 1, gw = w0 + px - 1;
        uint4 v = make_uint4(0u, 0u, 0u, 0u);
        if (gh >= 0 && gh < HGT && gw >= 0 && gw < WID)
            v = *(const uint4*)(inb + ((long)gh * WID + gw) * 32 + q * 8);
        *(uint4*)(&halo[(row * HALO_W2 + px) * CSTR + q * 8]) = v;
    }
    __syncthreads();

    const int lane = tid & 63, wid = tid >> 6;
    const int l15 = lane & 15, kg = lane >> 4;
    const int r = wid;
    const ushort* wlane = wpk + lane * 8;

    f32x4 acc[4];
#pragma unroll
    for (int f = 0; f < 4; ++f) acc[f] = (f32x4){0.f, 0.f, 0.f, 0.f};

#pragma unroll
    for (int tap = 0; tap < 9; ++tap) {
        const int dh = tap / 3, dw = tap - dh * 3;
        const bf16x8 a0 = *(const bf16x8*)(wlane + (tap * 2 + 0) * 512);
#pragma unroll
        for (int f = 0; f < 4; ++f) {
            const int c0 = f * 16;
            const bf16x8 bfv = *(const bf16x8*)(
                &halo[((r + dh) * HALO_W2 + (c0 + dw + l15)) * CSTR + kg * 8]);
            acc[f] = __builtin_amdgcn_mfma_f32_16x16x32_bf16(a0, bfv, acc[f], 0, 0, 0);
        }
    }

    if (kg == 0) {   // rows 0..2 of D valid
        const float b0 = bias[0], b1 = bias[1], b2v = bias[2];
#pragma unroll
        for (int f = 0; f < 4; ++f) {
            const int p = (h0 + r) * WID + (w0 + f * 16 + l15);
            const long gpx = (long)b * HWPX + p;
            float v0 = acc[f][0] + b0;
            float v1 = acc[f][1] + b1;
            float v2 = acc[f][2] + b2v;
            if (FINAL) {
                outp[(long)(b * 3 + 0) * HWPX + p] = v0 + img[(long)(b * 3 + 0) * HWPX + p];
                outp[(long)(b * 3 + 1) * HWPX + p] = v1 + img[(long)(b * 3 + 1) * HWPX + p];
                outp[(long)(b * 3 + 2) * HWPX + p] = v2 + img[(long)(b * 3 + 2) * HWPX + p];
            } else {
                uint2 u;
                u.x = pack2bf(v0, v1);
                u.y = pack2bf(v2, 0.f);
                *(uint2*)(comb + gpx * 8 + 4) = u;
            }
        }
    }

    if (!FINAL) {
        // fused trilinear LUT apply: 1 px/thread over the 8x64 tile
        const int row = tid >> 6, col = tid & 63;
        const int p = (h0 + row) * WID + (w0 + col);
        const float* rc = recon + (long)b * 3 * HWPX;
        float cr = fminf(fmaxf(rc[p] * 32.f, 0.f), 32.f);
        float cg = fminf(fmaxf(rc[HWPX + p] * 32.f, 0.f), 32.f);
        float cb = fminf(fmaxf(rc[2 * HWPX + p] * 32.f, 0.f), 32.f);
        float fr = fminf(floorf(cr), 31.f);
        float fg = fminf(floorf(cg), 31.f);
        float fb = fminf(floorf(cb), 31.f);
        float tr = cr - fr, tg = cg - fg, tb_ = cb - fb;
        int idx = (((int)fr * GSZ + (int)fg) * GSZ + (int)fb);
        float c[3];
#pragma unroll
        for (int ch = 0; ch < 3; ++ch) {
            const float* lut = clut + (long)(b * 3 + ch) * G3;
            float v000 = lut[idx],                  v001 = lut[idx + 1];
            float v010 = lut[idx + GSZ],            v011 = lut[idx + GSZ + 1];
            float v100 = lut[idx + GSZ * GSZ],      v101 = lut[idx + GSZ * GSZ + 1];
            float v110 = lut[idx + GSZ * GSZ + GSZ], v111 = lut[idx + GSZ * GSZ + GSZ + 1];
            float c00 = v000 + (v001 - v000) * tb_;
            float c01 = v010 + (v011 - v010) * tb_;
            float c10 = v100 + (v101 - v100) * tb_;
            float c11 = v110 + (v111 - v110) * tb_;
            float c0 = c00 + (c01 - c00) * tg;
            float c1 = c10 + (c11 - c10) * tg;
            c[ch] = c0 + (c1 - c0) * tr;
        }
        uint2 u;
        u.x = pack2bf(c[0], c[1]);
        u.y = pack2bf(c[2], 0.f);
        *(uint2*)(comb + ((long)b * HWPX + p) * 8) = u;
    }
}

// ---------------------------------------------------------------------------
// K8 v2: MFMA 6->32 conv. comb bf16 [px][8] staged to [11][66][8] LDS.
// k = tap*8+slot (K=96, 3 mfma x 2 halves); each B-frag = one b128 read
// (replaces the 64-scalar-ds_read_u16 gather).
// ---------------------------------------------------------------------------
__global__ __launch_bounds__(512) void conv_in6_mfma(
    const ushort* __restrict__ comb, const ushort* __restrict__ wpk6,
    const float* __restrict__ bias, ushort* __restrict__ out)
{
    __shared__ ushort chalo[HALO_H3 * HALO_W2 * 8];   // 11616 B
    __shared__ float s_bias[32];

    const int tid = threadIdx.x;
    const int bid = blockIdx.x;
    const int t   = (bid & 7) * CHUNK + (bid >> 3);
    const int tx  = t % NTX;
    const int rem = t / NTX;
    const int ty  = rem % NTY;
    const int b   = rem / NTY;
    const int h0 = ty * TH2;
    const int w0 = tx * TW2;

    if (tid < 32) s_bias[tid] = bias[tid];

    const ushort* cb = comb + (long)b * HWPX * 8;
    for (int i = tid; i < HALO_H3 * HALO_W2; i += 512) {
        const int row = i / HALO_W2, px = i - row * HALO_W2;
        const int gh = h0 + row - 1, gw = w0 + px - 1;
        uint4 v = make_uint4(0u, 0u, 0u, 0u);
        if (gh >= 0 && gh < HGT && gw >= 0 && gw < WID)
            v = *(const uint4*)(cb + ((long)gh * WID + gw) * 8);
        *(uint4*)(&chalo[i * 8]) = v;
    }
    __syncthreads();

    const int lane = tid & 63, wid = tid >> 6;
    const int l15 = lane & 15, kg = lane >> 4;
    const int r = wid;
    const ushort* wl6 = wpk6 + lane * 8;

    f32x4 acc[4][2];
#pragma unroll
    for (int f = 0; f < 4; ++f)
#pragma unroll
        for (int cf = 0; cf < 2; ++cf)
            acc[f][cf] = (f32x4){0.f, 0.f, 0.f, 0.f};

#pragma unroll
    for (int m = 0; m < 3; ++m) {
        const int tap = m * 4 + kg;            // 0..11 (taps>=9 zero-weighted)
        const int dh = tap / 3, dwp = tap - 3 * (tap / 3);
        const bf16x8 a0 = *(const bf16x8*)(wl6 + (m * 2 + 0) * 512);
        const bf16x8 a1 = *(const bf16x8*)(wl6 + (m * 2 + 1) * 512);
#pragma unroll
        for (int f = 0; f < 4; ++f) {
            const int c0 = f * 16;
            const bf16x8 bv = *(const bf16x8*)(
                &chalo[((r + dh) * HALO_W2 + (c0 + dwp + l15)) * 8]);
            acc[f][0] = __builtin_amdgcn_mfma_f32_16x16x32_bf16(a0, bv, acc[f][0], 0, 0, 0);
            acc[f][1] = __builtin_amdgcn_mfma_f32_16x16x32_bf16(a1, bv, acc[f][1], 0, 0, 0);
        }
    }

#pragma unroll
    for (int f = 0; f < 4; ++f) {
        const int c0 = f * 16;
        const long gpx = (long)b * HWPX + (long)(h0 + r) * WID + (w0 + c0 + l15);
#pragma unroll
        for (int cf = 0; cf < 2; ++cf) {
            const int co0 = cf * 16 + kg * 4;
            const float4 bv4 = *(const float4*)(&s_bias[co0]);
            uint2 o;
            o.x = pack2bf(gelu_f(acc[f][cf][0] + bv4.x), gelu_f(acc[f][cf][1] + bv4.y));
            o.y = pack2bf(gelu_f(acc[f][cf][2] + bv4.z), gelu_f(acc[f][cf][3] + bv4.w));
            *(uint2*)(out + gpx * 32 + co0) = o;
        }
    }
}

// ---------------------------------------------------------------------------
extern "C" void kernel_launch(void* const* d_in, const int* in_sizes, int n_in,
                              void* d_out, int out_size, void* d_ws, size_t ws_size,
                              hipStream_t stream)
{
    const int*   tokens  = (const int*)d_in[0];
    const float* img     = (const float*)d_in[1];
    const float* recon   = (const float*)d_in[2];
    const float* emb     = (const float*)d_in[3];
    const float* agg_w1  = (const float*)d_in[4];
    const float* agg_b1  = (const float*)d_in[5];
    const float* agg_w2  = (const float*)d_in[6];
    const float* agg_b2  = (const float*)d_in[7];
    const float* lut_w1  = (const float*)d_in[8];
    const float* lut_b1  = (const float*)d_in[9];
    const float* lut_w2  = (const float*)d_in[10];
    const float* lut_b2  = (const float*)d_in[11];
    const float* wg_w1   = (const float*)d_in[12];
    const float* wg_b1   = (const float*)d_in[13];
    const float* wg_w2   = (const float*)d_in[14];
    const float* wg_b2   = (const float*)d_in[15];
    const float* rp_cin_w = (const float*)d_in[16];
    const float* rp_cin_b = (const float*)d_in[17];
    const float* rp_rbA_w = (const float*)d_in[18];
    const float* rp_rbA_b = (const float*)d_in[19];
    const float* rp_rbA_g = (const float*)d_in[20];
    const float* rp_rbA_bt= (const float*)d_in[21];
    const float* rp_rbB_w = (const float*)d_in[22];
    const float* rp_rbB_b = (const float*)d_in[23];
    const float* rp_rbB_g = (const float*)d_in[24];
    const float* rp_rbB_bt= (const float*)d_in[25];
    const float* rp_cout_w= (const float*)d_in[26];
    const float* rp_cout_b= (const float*)d_in[27];
    const float* fu_cin_w = (const float*)d_in[28];
    const float* fu_cin_b = (const float*)d_in[29];
    const float* fu_rbA_w = (const float*)d_in[30];
    const float* fu_rbA_b = (const float*)d_in[31];
    const float* fu_rbA_g = (const float*)d_in[32];
    const float* fu_rbA_bt= (const float*)d_in[33];
    const float* fu_rbB_w = (const float*)d_in[34];
    const float* fu_rbB_b = (const float*)d_in[35];
    const float* fu_rbB_g = (const float*)d_in[36];
    const float* fu_rbB_bt= (const float*)d_in[37];
    const float* fu_cout_w= (const float*)d_in[38];
    const float* fu_cout_b= (const float*)d_in[39];

    float* ws = (float*)d_ws;
    float*  h3      = ws;                       // 1024
    float*  lwv     = ws + 1024;                // 32
    float*  partial = ws + 2048;                // 65536
    float*  clut    = ws + 69632;               // 431244
    ushort* wpack   = (ushort*)(ws + 524288);   // 61440 ushorts
    ushort* comb    = (ushort*)(ws + 589824);   // 4*HWPX*8 ushorts (bf16)
    ushort* act0    = (ushort*)(ws + 3145728);  // 18874368 ushorts
    ushort* act1    = (ushort*)(ws + 12582912);
    ushort* act2    = (ushort*)(ws + 22020096);
    float*  outp    = (float*)d_out;

    // pack all MFMA A-fragment tables
    pack_wconv_kernel<<<dim3(8), dim3(256), 0, stream>>>(
        rp_rbA_w, rp_rbB_w, fu_rbA_w, fu_rbB_w, rp_cout_w, fu_cout_w,
        fu_cin_w, rp_cin_w, wpack);

    // token head
    emb_partial_kernel<<<dim3(64, BB), dim3(256), 0, stream>>>(tokens, emb, partial);
    mlp_head_kernel<<<dim3(BB), dim3(1024), 0, stream>>>(
        partial, agg_w1, agg_b1, agg_w2, agg_b2,
        lut_w1, lut_b1, wg_w1, wg_b1, wg_w2, wg_b2, h3, lwv);

    // fused LUT GEMM + combine -> clut
    lut_fused_kernel<<<dim3((3 * G3 + 255) / 256), dim3(256), 0, stream>>>(
        h3, lwv, lut_w2, lut_b2, clut);

    const dim3 gm(NBLK), bm(512);

    // proc branch: img -> act0 -> act1 -> act2
    conv_in3_mfma<<<gm, bm, 0, stream>>>(img, wpack + WPK_IN3, rp_cin_b, act0);
    conv32_mfma<false><<<gm, bm, 0, stream>>>(
        act0, nullptr, wpack + 0 * 9216, rp_rbA_b, rp_rbA_g, rp_rbA_bt, act1);
    conv32_mfma<true><<<gm, bm, 0, stream>>>(
        act1, act0, wpack + 1 * 9216, rp_rbB_b, rp_rbB_g, rp_rbB_bt, act2);

    // proc 32->3 (MFMA) + fused LUT apply -> comb
    conv_out3_mfma<false><<<gm, bm, 0, stream>>>(
        act2, wpack + 4 * 9216, rp_cout_b, nullptr, nullptr, comb, clut, recon);

    // fuse branch: comb -> act0 -> act1 -> act2 -> d_out (+img)
    conv_in6_mfma<<<gm, bm, 0, stream>>>(comb, wpack + WPK_IN6, fu_cin_b, act0);
    conv32_mfma<false><<<gm, bm, 0, stream>>>(
        act0, nullptr, wpack + 2 * 9216, fu_rbA_b, fu_rbA_g, fu_rbA_bt, act1);
    conv32_mfma<true><<<gm, bm, 0, stream>>>(
        act1, act0, wpack + 3 * 9216, fu_rbB_b, fu_rbB_g, fu_rbB_bt, act2);
    conv_out3_mfma<true><<<gm, bm, 0, stream>>>(
        act2, wpack + 5 * 9216, fu_cout_b, img, outp, nullptr, nullptr, nullptr);
}